// Round 8
// baseline (425.463 us; speedup 1.0000x reference)
//
#include <hip/hip_runtime.h>
#include <hip/hip_bf16.h>
#include <math.h>

// Problem constants (from reference)
#define N_NODES  100000
#define N_EDGES  1200000
#define N_GRAPHS 100
#define SCAN_B   1024
#define XRNG     ((N_NODES + 7) / 8)   // 12500 nodes per XCD slice
#define NCH      32                    // edge chunks for CSR build
#define PARTS    16                    // pooling partials per graph

// ---------------------------------------------------------------------------
// CSR build with ZERO global atomics (XCD-sliced LDS histograms):
//  k_hist:  block (s,c) histograms chunk c's dst within slice s in LDS,
//           writes cnt[c][slice] coalesced.
//  k_colsum: deg = column-sum of cnt; scan -> row_ptr (+dinv fused).
//  k_cbase: per-node running prefix over chunks, in place: cnt[c][i] becomes
//           the base offset for (chunk c, node i).
//  k_fill2: re-scan with LDS rank; csr_src[cbase+rank] = src. Scattered
//           writes are XCD-L2-local (blockIdx%8 -> XCD round-robin).
// ---------------------------------------------------------------------------
__global__ __launch_bounds__(256) void k_hist(
    const int* __restrict__ dst, int* __restrict__ cnt, int e) {
    __shared__ int hist[XRNG];
    int r = blockIdx.x & 7;
    int c = blockIdx.x >> 3;
    int lo = r * XRNG;
    for (int j = threadIdx.x; j < XRNG; j += 256) hist[j] = 0;
    __syncthreads();
    int per = (e + NCH - 1) / NCH;
    int beg = c * per;
    int end = beg + per < e ? beg + per : e;
    for (int i = beg + threadIdx.x; i < end; i += 256) {
        int d = dst[i];
        if ((unsigned)(d - lo) < (unsigned)XRNG) atomicAdd(&hist[d - lo], 1);
    }
    __syncthreads();
    int* base = cnt + (size_t)c * N_NODES + lo;
    for (int j = threadIdx.x; j < XRNG; j += 256) base[j] = hist[j];
}

__global__ void k_colsum(const int* __restrict__ cnt, int* __restrict__ deg, int n) {
    int i = blockIdx.x * blockDim.x + threadIdx.x;
    if (i >= n) return;
    int s = 0;
    #pragma unroll 8
    for (int c = 0; c < NCH; c++) s += cnt[(size_t)c * n + i];
    deg[i] = s;
}

__global__ void k_cbase(int* __restrict__ cnt, const int* __restrict__ row_ptr, int n) {
    int i = blockIdx.x * blockDim.x + threadIdx.x;
    if (i >= n) return;
    int running = row_ptr[i];
    #pragma unroll 8
    for (int c = 0; c < NCH; c++) {
        int t = cnt[(size_t)c * n + i];
        cnt[(size_t)c * n + i] = running;
        running += t;
    }
}

__global__ __launch_bounds__(256) void k_fill2(
    const int* __restrict__ src, const int* __restrict__ dst,
    const int* __restrict__ cbase, int* __restrict__ csr_src, int e) {
    __shared__ int hist[XRNG];
    int r = blockIdx.x & 7;
    int c = blockIdx.x >> 3;
    int lo = r * XRNG;
    for (int j = threadIdx.x; j < XRNG; j += 256) hist[j] = 0;
    __syncthreads();
    int per = (e + NCH - 1) / NCH;
    int beg = c * per;
    int end = beg + per < e ? beg + per : e;
    const int* cb = cbase + (size_t)c * N_NODES;
    for (int i = beg + threadIdx.x; i < end; i += 256) {
        int d = dst[i];
        if ((unsigned)(d - lo) < (unsigned)XRNG) {
            int rank = atomicAdd(&hist[d - lo], 1);
            csr_src[cb[d] + rank] = src[i];
        }
    }
}

__global__ void k_block_sums(const int* __restrict__ deg, int* __restrict__ bsum, int n) {
    int i = blockIdx.x * SCAN_B + threadIdx.x;
    int v = (i < n) ? deg[i] : 0;
    #pragma unroll
    for (int d = 32; d > 0; d >>= 1) v += __shfl_xor(v, d);
    __shared__ int wsum[SCAN_B / 64];
    int lane = threadIdx.x & 63, w = threadIdx.x >> 6;
    if (lane == 0) wsum[w] = v;
    __syncthreads();
    if (threadIdx.x == 0) {
        int s = 0;
        #pragma unroll
        for (int k = 0; k < SCAN_B / 64; k++) s += wsum[k];
        bsum[blockIdx.x] = s;
    }
}

__global__ void k_scan_bsums(int* __restrict__ bsum, int nb) {
    __shared__ int s[256];
    int t = threadIdx.x;
    int v = (t < nb) ? bsum[t] : 0;
    s[t] = v;
    __syncthreads();
    for (int d = 1; d < 256; d <<= 1) {
        int u = (t >= d) ? s[t - d] : 0;
        __syncthreads();
        s[t] += u;
        __syncthreads();
    }
    if (t < nb) bsum[t] = s[t] - v;  // exclusive offset of block t
}

// scan deg -> row_ptr; also computes dinv = rsqrt(deg+1) (deg already loaded)
__global__ void k_scan_final(const int* __restrict__ deg, const int* __restrict__ bsum,
                             int* __restrict__ row_ptr, float* __restrict__ dinv,
                             int n, int n_edges) {
    int b = blockIdx.x;
    int i = b * SCAN_B + threadIdx.x;
    int v = (i < n) ? deg[i] : 0;
    int lane = threadIdx.x & 63, w = threadIdx.x >> 6;
    int inc = v;
    #pragma unroll
    for (int d = 1; d < 64; d <<= 1) {
        int u = __shfl_up(inc, d);
        if (lane >= d) inc += u;
    }
    __shared__ int wsum[SCAN_B / 64];
    __shared__ int woff[SCAN_B / 64];
    if (lane == 63) wsum[w] = inc;
    __syncthreads();
    if (threadIdx.x == 0) {
        int s = 0;
        #pragma unroll
        for (int k = 0; k < SCAN_B / 64; k++) { woff[k] = s; s += wsum[k]; }
    }
    __syncthreads();
    int excl = bsum[b] + woff[w] + (inc - v);
    if (i < n) {
        row_ptr[i] = excl;
        dinv[i] = rsqrtf((float)(v + 1));  // +1 self loop
    }
    if (b == 0 && threadIdx.x == 0) row_ptr[n] = n_edges;
}

// ---------------------------------------------------------------------------
// y0 = x * dinv, padded to stride 8.  [N,8] = 3.2 MB (fits one XCD L2)
// ---------------------------------------------------------------------------
__global__ void k_y0(const float* __restrict__ x, const float* __restrict__ dinv,
                     float* __restrict__ y0, int n) {
    int idx = blockIdx.x * blockDim.x + threadIdx.x;
    int node = idx >> 3, f = idx & 7;
    if (node >= n) return;
    float v = (f < 5) ? x[node * 5 + f] * dinv[node] : 0.f;
    y0[node * 8 + f] = v;
}

// ---------------------------------------------------------------------------
// Layer 1: s0 = (A+I) y0;  h1 = relu((dinv*s0)@W1 + b1);  y1 = dinv*h1  [N,32]
// one wave per node; 64 lanes = 8 edges x 8 feats
// ---------------------------------------------------------------------------
__global__ __launch_bounds__(256) void k_agg1(
    const int* __restrict__ row_ptr, const int* __restrict__ csr_src,
    const float* __restrict__ y0, const float* __restrict__ dinv,
    const float* __restrict__ W1, const float* __restrict__ b1,
    float* __restrict__ y1, int n) {
    int wave = (blockIdx.x * blockDim.x + threadIdx.x) >> 6;
    if (wave >= n) return;
    int lane = threadIdx.x & 63;
    int f = lane & 7, ec = lane >> 3;
    int start = row_ptr[wave], end = row_ptr[wave + 1];
    float acc = 0.f;
    for (int e = start + ec; e < end; e += 8) {
        int s = csr_src[e];
        acc += y0[s * 8 + f];
    }
    if (ec == 0) acc += y0[wave * 8 + f];   // self loop
    acc += __shfl_down(acc, 32);
    acc += __shfl_down(acc, 16);
    acc += __shfl_down(acc, 8);
    float di = dinv[wave];
    float s0[5];
    #pragma unroll
    for (int k = 0; k < 5; k++) s0[k] = __shfl(acc, k) * di;
    int fo = lane & 31;
    float hv = b1[fo];
    #pragma unroll
    for (int k = 0; k < 5; k++) hv += s0[k] * W1[k * 32 + fo];
    hv = hv > 0.f ? hv : 0.f;
    if (lane < 32) y1[wave * 32 + lane] = hv * di;
}

// ---------------------------------------------------------------------------
// Layer 2 gather only:  sv = dinv * ((A+I) y1)   [N,32]
// wave per node, half-wave edge split, 4-way unroll, no LDS -> max occupancy
// ---------------------------------------------------------------------------
__global__ __launch_bounds__(256) void k_agg2g(
    const int* __restrict__ row_ptr, const int* __restrict__ csr_src,
    const float* __restrict__ y1, const float* __restrict__ dinv,
    float* __restrict__ sv, int n) {
    int wave = (blockIdx.x * blockDim.x + threadIdx.x) >> 6;
    if (wave >= n) return;
    int lane = threadIdx.x & 63;
    int f = lane & 31, hh = lane >> 5;
    int start = row_ptr[wave], end = row_ptr[wave + 1];
    float a0 = 0.f, a1 = 0.f, a2 = 0.f, a3 = 0.f;
    int e = start + hh;
    for (; e + 6 < end; e += 8) {
        int s0 = csr_src[e],     s1i = csr_src[e + 2];
        int s2 = csr_src[e + 4], s3i = csr_src[e + 6];
        a0 += y1[s0 * 32 + f];
        a1 += y1[s1i * 32 + f];
        a2 += y1[s2 * 32 + f];
        a3 += y1[s3i * 32 + f];
    }
    for (; e < end; e += 2) a0 += y1[csr_src[e] * 32 + f];
    float acc = (a0 + a1) + (a2 + a3);
    acc += __shfl_xor(acc, 32);
    acc += y1[wave * 32 + f];            // self loop
    if (lane < 32) sv[wave * 32 + lane] = acc * dinv[wave];
}

// ---------------------------------------------------------------------------
// Fused dense part of layer 2 as register-tiled f32 GEMM, 64-node tiles:
//   h2 = relu(sv @ W2 + b2)   [64 x 64]   (kept transposed in LDS)
//   h  = h2 @ nn1W + nn1b     [64 x 124]
// ---------------------------------------------------------------------------
#define LTS 68   // padded row stride for transposed tiles (x4B, 16B-aligned)
__global__ __launch_bounds__(256) void k_l2mm(
    const float* __restrict__ sv, const float* __restrict__ W2,
    const float* __restrict__ b2, const float* __restrict__ nn1W,
    const float* __restrict__ nn1b, float* __restrict__ h, int n) {
    __shared__ float lsW2[32 * 64];      // [k][f] stride 64, 8 KB
    __shared__ float lsN[64 * 128];      // [k][f] stride 128 (124 padded), 32 KB
    __shared__ float lsT[64 * LTS];      // union: svT[32][.] then h2T[64][.], 17.4 KB

    int tid = threadIdx.x;
    int nb = blockIdx.x * 64;

    // stage W2 [32][64]
    #pragma unroll
    for (int i = 0; i < 8; i++) lsW2[tid + i * 256] = W2[tid + i * 256];
    // stage nn1W [64][124] -> [64][128], zero the pad
    for (int idx = tid; idx < 64 * 124; idx += 256)
        lsN[(idx / 124) * 128 + (idx % 124)] = nn1W[idx];
    if (tid < 256) lsN[(tid >> 2) * 128 + 124 + (tid & 3)] = 0.f;
    // stage sv tile transposed: svT[k][node] = lsT[k*LTS + node]
    {
        int node = tid >> 2, kq = (tid & 3) * 8;
        float4 v0, v1;
        if (nb + node < n) {
            v0 = *(const float4*)&sv[(size_t)(nb + node) * 32 + kq];
            v1 = *(const float4*)&sv[(size_t)(nb + node) * 32 + kq + 4];
        } else {
            v0 = make_float4(0.f, 0.f, 0.f, 0.f); v1 = v0;
        }
        lsT[(kq + 0) * LTS + node] = v0.x;
        lsT[(kq + 1) * LTS + node] = v0.y;
        lsT[(kq + 2) * LTS + node] = v0.z;
        lsT[(kq + 3) * LTS + node] = v0.w;
        lsT[(kq + 4) * LTS + node] = v1.x;
        lsT[(kq + 5) * LTS + node] = v1.y;
        lsT[(kq + 6) * LTS + node] = v1.z;
        lsT[(kq + 7) * LTS + node] = v1.w;
    }
    __syncthreads();

    int tf = tid & 15;   // feature quad
    int tn = tid >> 4;   // node quad

    // GEMM1: c1[i][j] = sum_k svT[k][tn*4+i] * W2[k][tf*4+j]
    float c1[4][4] = {};
    #pragma unroll 4
    for (int k = 0; k < 32; k++) {
        float4 a = *(const float4*)&lsT[k * LTS + tn * 4];
        float4 w = *(const float4*)&lsW2[k * 64 + tf * 4];
        const float av[4] = {a.x, a.y, a.z, a.w};
        const float wv[4] = {w.x, w.y, w.z, w.w};
        #pragma unroll
        for (int i = 0; i < 4; i++)
            #pragma unroll
            for (int j = 0; j < 4; j++) c1[i][j] += av[i] * wv[j];
    }
    __syncthreads();   // done reading svT
    // relu(+b2), write h2 transposed: h2T[f][node]
    {
        float4 bb = *(const float4*)&b2[tf * 4];
        const float bv[4] = {bb.x, bb.y, bb.z, bb.w};
        #pragma unroll
        for (int j = 0; j < 4; j++) {
            float4 col;
            col.x = fmaxf(c1[0][j] + bv[j], 0.f);
            col.y = fmaxf(c1[1][j] + bv[j], 0.f);
            col.z = fmaxf(c1[2][j] + bv[j], 0.f);
            col.w = fmaxf(c1[3][j] + bv[j], 0.f);
            *(float4*)&lsT[(tf * 4 + j) * LTS + tn * 4] = col;
        }
    }
    __syncthreads();

    // GEMM2: c2a (feats tf*4..+3), c2b (feats 64+tf*4..+3)
    float c2a[4][4] = {}, c2b[4][4] = {};
    #pragma unroll 2
    for (int k = 0; k < 64; k++) {
        float4 a  = *(const float4*)&lsT[k * LTS + tn * 4];
        float4 w1 = *(const float4*)&lsN[k * 128 + tf * 4];
        float4 w2 = *(const float4*)&lsN[k * 128 + 64 + tf * 4];
        const float av[4] = {a.x, a.y, a.z, a.w};
        const float w1v[4] = {w1.x, w1.y, w1.z, w1.w};
        const float w2v[4] = {w2.x, w2.y, w2.z, w2.w};
        #pragma unroll
        for (int i = 0; i < 4; i++)
            #pragma unroll
            for (int j = 0; j < 4; j++) {
                c2a[i][j] += av[i] * w1v[j];
                c2b[i][j] += av[i] * w2v[j];
            }
    }
    // epilogue: + nn1b, store h rows (stride 124, 16B-aligned quads)
    {
        float4 ba = *(const float4*)&nn1b[tf * 4];
        const float bav[4] = {ba.x, ba.y, ba.z, ba.w};
        float bbv[4] = {0.f, 0.f, 0.f, 0.f};
        if (tf < 15) {
            float4 bb = *(const float4*)&nn1b[64 + tf * 4];
            bbv[0] = bb.x; bbv[1] = bb.y; bbv[2] = bb.z; bbv[3] = bb.w;
        }
        #pragma unroll
        for (int i = 0; i < 4; i++) {
            int node = nb + tn * 4 + i;
            if (node >= n) break;
            float4 oa, ob;
            oa.x = c2a[i][0] + bav[0]; oa.y = c2a[i][1] + bav[1];
            oa.z = c2a[i][2] + bav[2]; oa.w = c2a[i][3] + bav[3];
            *(float4*)&h[(size_t)node * 124 + tf * 4] = oa;
            if (tf < 15) {
                ob.x = c2b[i][0] + bbv[0]; ob.y = c2b[i][1] + bbv[1];
                ob.z = c2b[i][2] + bbv[2]; ob.w = c2b[i][3] + bbv[3];
                *(float4*)&h[(size_t)node * 124 + 64 + tf * 4] = ob;
            }
        }
    }
}

// ---------------------------------------------------------------------------
// Pooling phase A: G*PARTS blocks; block (g,r) reduces an interleaved slice
// of graph g's contiguous node range into partial[g][r][128] (max/min/sum).
// Graph bounds found by inline binary search on the sorted batch vector.
// ---------------------------------------------------------------------------
__global__ __launch_bounds__(512) void k_pool_a(
    const float* __restrict__ h, const int* __restrict__ batch,
    float* __restrict__ pmax, float* __restrict__ pmin, float* __restrict__ psum,
    int n) {
    int g = blockIdx.x / PARTS, r = blockIdx.x % PARTS;
    __shared__ int sb[2];
    if (threadIdx.x < 2) {
        int target = g + threadIdx.x;
        int lo = 0, hi = n;
        while (lo < hi) {
            int mid = (lo + hi) >> 1;
            if (batch[mid] < target) lo = mid + 1; else hi = mid;
        }
        sb[threadIdx.x] = lo;
    }
    __syncthreads();
    int start = sb[0], end = sb[1];
    int t = threadIdx.x;
    int f = t & 127, r2 = t >> 7;  // r2 in 0..3
    float vmax = -INFINITY, vmin = INFINITY, vsum = 0.f;
    if (f < 124) {
        for (int node = start + r * 4 + r2; node < end; node += PARTS * 4) {
            float v = h[(size_t)node * 124 + f];
            vmax = fmaxf(vmax, v);
            vmin = fminf(vmin, v);
            vsum += v;
        }
    }
    __shared__ float smax[4][128], smin[4][128], ssum[4][128];
    smax[r2][f] = vmax; smin[r2][f] = vmin; ssum[r2][f] = vsum;
    __syncthreads();
    if (r2 == 0) {
        #pragma unroll
        for (int k = 1; k < 4; k++) {
            vmax = fmaxf(vmax, smax[k][f]);
            vmin = fminf(vmin, smin[k][f]);
            vsum += ssum[k][f];
        }
        int idx = (g * PARTS + r) * 128 + f;
        pmax[idx] = vmax; pmin[idx] = vmin; psum[idx] = vsum;
    }
}

// ---------------------------------------------------------------------------
// Fused pooling-fold + head, one block per graph:
//  grelu row (496) built in LDS from the PARTS partials + epilogue, then
//  g1 = grelu@nn2_W + nn2_b (NO relu);  conv4 == plain linear;
//  g2 = relu(g1@W4+b4); g3 = relu(g2@nn3_W+nn3_b); out = g3@nn4_W + nn4_b
// ---------------------------------------------------------------------------
__global__ __launch_bounds__(256) void k_head(
    const float* __restrict__ pmax, const float* __restrict__ pmin,
    const float* __restrict__ psum, const int* __restrict__ batch,
    const float* __restrict__ nn2W, const float* __restrict__ nn2b,
    const float* __restrict__ W4,   const float* __restrict__ b4,
    const float* __restrict__ nn3W, const float* __restrict__ nn3b,
    const float* __restrict__ nn4W, const float* __restrict__ nn4b,
    float* __restrict__ out, int n) {
    int g = blockIdx.x, tid = threadIdx.x;
    int lane = tid & 63, w = tid >> 6;
    __shared__ float lg[496];
    __shared__ float part[4][64];
    __shared__ int sb[2];
    if (tid < 2) {
        int target = g + tid;
        int lo = 0, hi = n;
        while (lo < hi) {
            int mid = (lo + hi) >> 1;
            if (batch[mid] < target) lo = mid + 1; else hi = mid;
        }
        sb[tid] = lo;
    }
    __syncthreads();
    if (tid < 124) {
        float vmax = -INFINITY, vmin = INFINITY, vsum = 0.f;
        #pragma unroll 4
        for (int r = 0; r < PARTS; r++) {
            int idx = (g * PARTS + r) * 128 + tid;
            vmax = fmaxf(vmax, pmax[idx]);
            vmin = fminf(vmin, pmin[idx]);
            vsum += psum[idx];
        }
        int cnt = sb[1] - sb[0];
        float a = (cnt > 0) ? vmax : 0.f;
        float b = (cnt > 0) ? vmin : 0.f;
        lg[tid]       = fmaxf(a, 0.f);
        lg[124 + tid] = fmaxf(b, 0.f);
        lg[248 + tid] = fmaxf(vsum, 0.f);
        lg[372 + tid] = fmaxf(vsum / fmaxf((float)cnt, 1.f), 0.f);
    }
    __syncthreads();
    float acc = 0.f;
    int k0 = w * 124;
    #pragma unroll 4
    for (int k = k0; k < k0 + 124; k++)
        acc += lg[k] * nn2W[k * 64 + lane];
    part[w][lane] = acc;
    __syncthreads();
    if (w == 0) {
        float g1 = part[0][lane] + part[1][lane] + part[2][lane] + part[3][lane]
                 + nn2b[lane];
        float acc2 = (lane < 32) ? b4[lane] : 0.f;
        #pragma unroll 8
        for (int k = 0; k < 64; k++) {
            float v = __shfl(g1, k);
            if (lane < 32) acc2 += v * W4[k * 32 + lane];
        }
        float g2 = fmaxf(acc2, 0.f);
        float acc3 = (lane < 16) ? nn3b[lane] : 0.f;
        #pragma unroll 8
        for (int k = 0; k < 32; k++) {
            float v = __shfl(g2, k);
            if (lane < 16) acc3 += v * nn3W[k * 16 + lane];
        }
        float g3 = fmaxf(acc3, 0.f);
        float p = (lane < 16) ? g3 * nn4W[lane] : 0.f;
        p += __shfl_xor(p, 8);
        p += __shfl_xor(p, 4);
        p += __shfl_xor(p, 2);
        p += __shfl_xor(p, 1);
        if (lane == 0) out[g] = p + nn4b[0];
    }
}

// ---------------------------------------------------------------------------
extern "C" void kernel_launch(void* const* d_in, const int* in_sizes, int n_in,
                              void* d_out, int out_size, void* d_ws, size_t ws_size,
                              hipStream_t stream) {
    const int N = N_NODES, E = N_EDGES, G = N_GRAPHS;

    const float* x     = (const float*)d_in[0];
    const int*   ei    = (const int*)d_in[1];
    const int*   batch = (const int*)d_in[2];
    const float* W1    = (const float*)d_in[3];
    const float* b1    = (const float*)d_in[4];
    const float* W2    = (const float*)d_in[5];
    const float* b2    = (const float*)d_in[6];
    const float* nn1W  = (const float*)d_in[7];
    const float* nn1b  = (const float*)d_in[8];
    const float* nn2W  = (const float*)d_in[9];
    const float* nn2b  = (const float*)d_in[10];
    const float* W4    = (const float*)d_in[11];
    const float* b4    = (const float*)d_in[12];
    const float* nn3W  = (const float*)d_in[13];
    const float* nn3b  = (const float*)d_in[14];
    const float* nn4W  = (const float*)d_in[15];
    const float* nn4b  = (const float*)d_in[16];

    const int* src = ei;       // edge_index[0]
    const int* dst = ei + E;   // edge_index[1]

    char* ws = (char*)d_ws;
    size_t off = 0;
    auto alloc = [&](size_t bytes) -> char* {
        char* p = ws + off;
        off += (bytes + 255) & ~(size_t)255;
        return p;
    };
    int*   deg     = (int*)  alloc((size_t)N * 4);
    float* dinv    = (float*)alloc((size_t)N * 4);
    int*   row_ptr = (int*)  alloc((size_t)(N + 1) * 4);
    int*   bsum    = (int*)  alloc(1024 * 4);
    int*   csr_src = (int*)  alloc((size_t)E * 4);
    float* y0      = (float*)alloc((size_t)N * 8 * 4);
    float* y1      = (float*)alloc((size_t)N * 32 * 4);
    float* sv      = (float*)alloc((size_t)N * 32 * 4);
    float* h       = (float*)alloc((size_t)N * 124 * 4);
    float* pmax    = (float*)alloc((size_t)G * PARTS * 128 * 4);
    float* pmin    = (float*)alloc((size_t)G * PARTS * 128 * 4);
    float* psum    = (float*)alloc((size_t)G * PARTS * 128 * 4);
    (void)ws_size;

    // cnt[NCH][N] aliases h: used strictly before k_l2mm writes h
    int* cnt = (int*)h;   // NCH*N*4 = 12.8 MB <= 49.6 MB

    float* out = (float*)d_out;

    const int NB = (N + SCAN_B - 1) / SCAN_B;  // 98

    k_hist<<<NCH * 8, 256, 0, stream>>>(dst, cnt, E);
    k_colsum<<<(N + 255) / 256, 256, 0, stream>>>(cnt, deg, N);
    k_block_sums<<<NB, SCAN_B, 0, stream>>>(deg, bsum, N);
    k_scan_bsums<<<1, 256, 0, stream>>>(bsum, NB);
    k_scan_final<<<NB, SCAN_B, 0, stream>>>(deg, bsum, row_ptr, dinv, N, E);
    k_cbase<<<(N + 255) / 256, 256, 0, stream>>>(cnt, row_ptr, N);
    k_fill2<<<NCH * 8, 256, 0, stream>>>(src, dst, cnt, csr_src, E);
    k_y0<<<(N * 8 + 255) / 256, 256, 0, stream>>>(x, dinv, y0, N);
    k_agg1<<<(N + 3) / 4, 256, 0, stream>>>(row_ptr, csr_src, y0, dinv, W1, b1, y1, N);
    k_agg2g<<<(N + 3) / 4, 256, 0, stream>>>(row_ptr, csr_src, y1, dinv, sv, N);
    k_l2mm<<<(N + 63) / 64, 256, 0, stream>>>(sv, W2, b2, nn1W, nn1b, h, N);
    k_pool_a<<<G * PARTS, 512, 0, stream>>>(h, batch, pmax, pmin, psum, N);
    k_head<<<G, 256, 0, stream>>>(pmax, pmin, psum, batch, nn2W, nn2b, W4, b4,
                                  nn3W, nn3b, nn4W, nn4b, out, N);
}

// Round 9
// 346.371 us; speedup vs baseline: 1.2283x; 1.2283x over previous
//
#include <hip/hip_runtime.h>
#include <hip/hip_bf16.h>
#include <math.h>

// Problem constants (from reference)
#define N_NODES  100000
#define N_EDGES  1200000
#define N_GRAPHS 100
#define SCAN_B   1024
#define XRNG     ((N_NODES + 7) / 8)   // 12500 nodes per XCD slice
#define PARTS    16                    // pooling partials per graph

// ---------------------------------------------------------------------------
// CSR build, atomic-light two-pass (round-7 proven config):
//  Pass A (k_degslot): slotpos[i] = atomicAdd(deg[dst[i]],1) — ONE edge pass,
//    the only global atomics; slotpos written coalesced.
//  scan (deg -> row_ptr), dinv + y0 fused in.
//  Pass B (k_fill_x): csr_src[row_ptr[d]+slotpos[i]] = src[i] — ZERO atomics,
//    XCD-sliced (blockIdx%8 -> XCD round-robin) so each written line is owned
//    by one XCD's L2 (no partial-line write amplification).
// ---------------------------------------------------------------------------
__global__ void k_degslot(const int* __restrict__ dst, int* __restrict__ deg,
                          int* __restrict__ slotpos, int e) {
    int i = blockIdx.x * blockDim.x + threadIdx.x;
    if (i < e) slotpos[i] = atomicAdd(&deg[dst[i]], 1);
}

__global__ __launch_bounds__(256) void k_fill_x(
    const int* __restrict__ src, const int* __restrict__ dst,
    const int* __restrict__ slotpos, const int* __restrict__ row_ptr,
    int* __restrict__ csr_src, int e, int nchunk) {
    int r = blockIdx.x & 7;
    int chunk = blockIdx.x >> 3;
    int lo = r * XRNG;
    int per = (e + nchunk - 1) / nchunk;
    int beg = chunk * per;
    int end = beg + per < e ? beg + per : e;
    for (int i = beg + threadIdx.x; i < end; i += 256) {
        int d = dst[i];
        if ((unsigned)(d - lo) < (unsigned)XRNG)
            csr_src[row_ptr[d] + slotpos[i]] = src[i];
    }
}

__global__ void k_block_sums(const int* __restrict__ deg, int* __restrict__ bsum, int n) {
    int i = blockIdx.x * SCAN_B + threadIdx.x;
    int v = (i < n) ? deg[i] : 0;
    #pragma unroll
    for (int d = 32; d > 0; d >>= 1) v += __shfl_xor(v, d);
    __shared__ int wsum[SCAN_B / 64];
    int lane = threadIdx.x & 63, w = threadIdx.x >> 6;
    if (lane == 0) wsum[w] = v;
    __syncthreads();
    if (threadIdx.x == 0) {
        int s = 0;
        #pragma unroll
        for (int k = 0; k < SCAN_B / 64; k++) s += wsum[k];
        bsum[blockIdx.x] = s;
    }
}

__global__ void k_scan_bsums(int* __restrict__ bsum, int nb) {
    __shared__ int s[256];
    int t = threadIdx.x;
    int v = (t < nb) ? bsum[t] : 0;
    s[t] = v;
    __syncthreads();
    for (int d = 1; d < 256; d <<= 1) {
        int u = (t >= d) ? s[t - d] : 0;
        __syncthreads();
        s[t] += u;
        __syncthreads();
    }
    if (t < nb) bsum[t] = s[t] - v;  // exclusive offset of block t
}

// scan deg -> row_ptr; fuses dinv = rsqrt(deg+1) AND y0 = x*dinv (stride 8)
__global__ void k_scan_final(const int* __restrict__ deg, const int* __restrict__ bsum,
                             const float* __restrict__ x,
                             int* __restrict__ row_ptr, float* __restrict__ dinv,
                             float* __restrict__ y0, int n, int n_edges) {
    int b = blockIdx.x;
    int i = b * SCAN_B + threadIdx.x;
    int v = (i < n) ? deg[i] : 0;
    int lane = threadIdx.x & 63, w = threadIdx.x >> 6;
    int inc = v;
    #pragma unroll
    for (int d = 1; d < 64; d <<= 1) {
        int u = __shfl_up(inc, d);
        if (lane >= d) inc += u;
    }
    __shared__ int wsum[SCAN_B / 64];
    __shared__ int woff[SCAN_B / 64];
    if (lane == 63) wsum[w] = inc;
    __syncthreads();
    if (threadIdx.x == 0) {
        int s = 0;
        #pragma unroll
        for (int k = 0; k < SCAN_B / 64; k++) { woff[k] = s; s += wsum[k]; }
    }
    __syncthreads();
    int excl = bsum[b] + woff[w] + (inc - v);
    if (i < n) {
        row_ptr[i] = excl;
        float di = rsqrtf((float)(v + 1));  // +1 self loop
        dinv[i] = di;
        float4 q0, q1;
        q0.x = x[i * 5 + 0] * di;
        q0.y = x[i * 5 + 1] * di;
        q0.z = x[i * 5 + 2] * di;
        q0.w = x[i * 5 + 3] * di;
        q1.x = x[i * 5 + 4] * di;
        q1.y = 0.f; q1.z = 0.f; q1.w = 0.f;
        *(float4*)&y0[(size_t)i * 8]     = q0;
        *(float4*)&y0[(size_t)i * 8 + 4] = q1;
    }
    if (b == 0 && threadIdx.x == 0) row_ptr[n] = n_edges;
}

// ---------------------------------------------------------------------------
// Layer 1: s0 = (A+I) y0;  h1 = relu((dinv*s0)@W1 + b1);  y1 = dinv*h1  [N,32]
// one wave per node; 64 lanes = 8 edges x 8 feats (y0 stride 8, 3.2MB -> L2)
// ---------------------------------------------------------------------------
__global__ __launch_bounds__(256) void k_agg1(
    const int* __restrict__ row_ptr, const int* __restrict__ csr_src,
    const float* __restrict__ y0, const float* __restrict__ dinv,
    const float* __restrict__ W1, const float* __restrict__ b1,
    float* __restrict__ y1, int n) {
    int wave = (blockIdx.x * blockDim.x + threadIdx.x) >> 6;
    if (wave >= n) return;
    int lane = threadIdx.x & 63;
    int f = lane & 7, ec = lane >> 3;
    int start = row_ptr[wave], end = row_ptr[wave + 1];
    float acc = 0.f;
    for (int e = start + ec; e < end; e += 8) {
        int s = csr_src[e];
        acc += y0[(size_t)s * 8 + f];
    }
    if (ec == 0) acc += y0[(size_t)wave * 8 + f];   // self loop
    acc += __shfl_down(acc, 32);
    acc += __shfl_down(acc, 16);
    acc += __shfl_down(acc, 8);
    float di = dinv[wave];
    float s0[5];
    #pragma unroll
    for (int k = 0; k < 5; k++) s0[k] = __shfl(acc, k) * di;
    int fo = lane & 31;
    float hv = b1[fo];
    #pragma unroll
    for (int k = 0; k < 5; k++) hv += s0[k] * W1[k * 32 + fo];
    hv = hv > 0.f ? hv : 0.f;
    if (lane < 32) y1[(size_t)wave * 32 + lane] = hv * di;
}

// ---------------------------------------------------------------------------
// Layer 2 gather only:  sv = dinv * ((A+I) y1)   [N,32]
// one wave per node; 64 lanes = 8 edges (ec) x 8 float4-quads (fq) ->
// 16B/lane gathers, 4x fewer VMEM instrs than scalar; 2-way unroll = 16
// edges in flight. Cross-edge reduce via 12 shuffles; lanes 0..7 store
// the 128B sv row coalesced.
// ---------------------------------------------------------------------------
__global__ __launch_bounds__(256) void k_agg2g(
    const int* __restrict__ row_ptr, const int* __restrict__ csr_src,
    const float* __restrict__ y1, const float* __restrict__ dinv,
    float* __restrict__ sv, int n) {
    int wave = (blockIdx.x * blockDim.x + threadIdx.x) >> 6;
    if (wave >= n) return;
    int lane = threadIdx.x & 63;
    int ec = lane >> 3, fq = lane & 7;
    int start = row_ptr[wave], end = row_ptr[wave + 1];
    float4 a0 = make_float4(0.f, 0.f, 0.f, 0.f);
    float4 a1 = make_float4(0.f, 0.f, 0.f, 0.f);
    int e = start + ec;
    for (; e + 8 < end; e += 16) {
        int s0 = csr_src[e], s1 = csr_src[e + 8];
        float4 v0 = *(const float4*)&y1[(size_t)s0 * 32 + fq * 4];
        float4 v1 = *(const float4*)&y1[(size_t)s1 * 32 + fq * 4];
        a0.x += v0.x; a0.y += v0.y; a0.z += v0.z; a0.w += v0.w;
        a1.x += v1.x; a1.y += v1.y; a1.z += v1.z; a1.w += v1.w;
    }
    for (; e < end; e += 8) {
        int s0 = csr_src[e];
        float4 v0 = *(const float4*)&y1[(size_t)s0 * 32 + fq * 4];
        a0.x += v0.x; a0.y += v0.y; a0.z += v0.z; a0.w += v0.w;
    }
    a0.x += a1.x; a0.y += a1.y; a0.z += a1.z; a0.w += a1.w;
    if (ec == 0) {   // self loop
        float4 sl = *(const float4*)&y1[(size_t)wave * 32 + fq * 4];
        a0.x += sl.x; a0.y += sl.y; a0.z += sl.z; a0.w += sl.w;
    }
    // reduce across ec (lane stride 8): +32, +16, +8 -> totals in lanes 0..7
    a0.x += __shfl_down(a0.x, 32); a0.y += __shfl_down(a0.y, 32);
    a0.z += __shfl_down(a0.z, 32); a0.w += __shfl_down(a0.w, 32);
    a0.x += __shfl_down(a0.x, 16); a0.y += __shfl_down(a0.y, 16);
    a0.z += __shfl_down(a0.z, 16); a0.w += __shfl_down(a0.w, 16);
    a0.x += __shfl_down(a0.x, 8);  a0.y += __shfl_down(a0.y, 8);
    a0.z += __shfl_down(a0.z, 8);  a0.w += __shfl_down(a0.w, 8);
    if (lane < 8) {
        float di = dinv[wave];
        float4 r;
        r.x = a0.x * di; r.y = a0.y * di; r.z = a0.z * di; r.w = a0.w * di;
        *(float4*)&sv[(size_t)wave * 32 + fq * 4] = r;
    }
}

// ---------------------------------------------------------------------------
// Fused dense part of layer 2 as register-tiled f32 GEMM, 64-node tiles:
//   h2 = relu(sv @ W2 + b2)   [64 x 64]   (kept transposed in LDS)
//   h  = h2 @ nn1W + nn1b     [64 x 124]
// ---------------------------------------------------------------------------
#define LTS 68   // padded row stride for transposed tiles (x4B, 16B-aligned)
__global__ __launch_bounds__(256) void k_l2mm(
    const float* __restrict__ sv, const float* __restrict__ W2,
    const float* __restrict__ b2, const float* __restrict__ nn1W,
    const float* __restrict__ nn1b, float* __restrict__ h, int n) {
    __shared__ float lsW2[32 * 64];      // [k][f] stride 64, 8 KB
    __shared__ float lsN[64 * 128];      // [k][f] stride 128 (124 padded), 32 KB
    __shared__ float lsT[64 * LTS];      // union: svT[32][.] then h2T[64][.], 17.4 KB

    int tid = threadIdx.x;
    int nb = blockIdx.x * 64;

    // stage W2 [32][64]
    #pragma unroll
    for (int i = 0; i < 8; i++) lsW2[tid + i * 256] = W2[tid + i * 256];
    // stage nn1W [64][124] -> [64][128], zero the pad
    for (int idx = tid; idx < 64 * 124; idx += 256)
        lsN[(idx / 124) * 128 + (idx % 124)] = nn1W[idx];
    if (tid < 256) lsN[(tid >> 2) * 128 + 124 + (tid & 3)] = 0.f;
    // stage sv tile transposed: svT[k][node] = lsT[k*LTS + node]
    {
        int node = tid >> 2, kq = (tid & 3) * 8;
        float4 v0, v1;
        if (nb + node < n) {
            v0 = *(const float4*)&sv[(size_t)(nb + node) * 32 + kq];
            v1 = *(const float4*)&sv[(size_t)(nb + node) * 32 + kq + 4];
        } else {
            v0 = make_float4(0.f, 0.f, 0.f, 0.f); v1 = v0;
        }
        lsT[(kq + 0) * LTS + node] = v0.x;
        lsT[(kq + 1) * LTS + node] = v0.y;
        lsT[(kq + 2) * LTS + node] = v0.z;
        lsT[(kq + 3) * LTS + node] = v0.w;
        lsT[(kq + 4) * LTS + node] = v1.x;
        lsT[(kq + 5) * LTS + node] = v1.y;
        lsT[(kq + 6) * LTS + node] = v1.z;
        lsT[(kq + 7) * LTS + node] = v1.w;
    }
    __syncthreads();

    int tf = tid & 15;   // feature quad
    int tn = tid >> 4;   // node quad

    // GEMM1: c1[i][j] = sum_k svT[k][tn*4+i] * W2[k][tf*4+j]
    float c1[4][4] = {};
    #pragma unroll 4
    for (int k = 0; k < 32; k++) {
        float4 a = *(const float4*)&lsT[k * LTS + tn * 4];
        float4 w = *(const float4*)&lsW2[k * 64 + tf * 4];
        const float av[4] = {a.x, a.y, a.z, a.w};
        const float wv[4] = {w.x, w.y, w.z, w.w};
        #pragma unroll
        for (int i = 0; i < 4; i++)
            #pragma unroll
            for (int j = 0; j < 4; j++) c1[i][j] += av[i] * wv[j];
    }
    __syncthreads();   // done reading svT
    // relu(+b2), write h2 transposed: h2T[f][node]
    {
        float4 bb = *(const float4*)&b2[tf * 4];
        const float bv[4] = {bb.x, bb.y, bb.z, bb.w};
        #pragma unroll
        for (int j = 0; j < 4; j++) {
            float4 col;
            col.x = fmaxf(c1[0][j] + bv[j], 0.f);
            col.y = fmaxf(c1[1][j] + bv[j], 0.f);
            col.z = fmaxf(c1[2][j] + bv[j], 0.f);
            col.w = fmaxf(c1[3][j] + bv[j], 0.f);
            *(float4*)&lsT[(tf * 4 + j) * LTS + tn * 4] = col;
        }
    }
    __syncthreads();

    // GEMM2: c2a (feats tf*4..+3), c2b (feats 64+tf*4..+3)
    float c2a[4][4] = {}, c2b[4][4] = {};
    #pragma unroll 2
    for (int k = 0; k < 64; k++) {
        float4 a  = *(const float4*)&lsT[k * LTS + tn * 4];
        float4 w1 = *(const float4*)&lsN[k * 128 + tf * 4];
        float4 w2 = *(const float4*)&lsN[k * 128 + 64 + tf * 4];
        const float av[4] = {a.x, a.y, a.z, a.w};
        const float w1v[4] = {w1.x, w1.y, w1.z, w1.w};
        const float w2v[4] = {w2.x, w2.y, w2.z, w2.w};
        #pragma unroll
        for (int i = 0; i < 4; i++)
            #pragma unroll
            for (int j = 0; j < 4; j++) {
                c2a[i][j] += av[i] * w1v[j];
                c2b[i][j] += av[i] * w2v[j];
            }
    }
    // epilogue: + nn1b, store h rows (stride 124, 16B-aligned quads)
    {
        float4 ba = *(const float4*)&nn1b[tf * 4];
        const float bav[4] = {ba.x, ba.y, ba.z, ba.w};
        float bbv[4] = {0.f, 0.f, 0.f, 0.f};
        if (tf < 15) {
            float4 bb = *(const float4*)&nn1b[64 + tf * 4];
            bbv[0] = bb.x; bbv[1] = bb.y; bbv[2] = bb.z; bbv[3] = bb.w;
        }
        #pragma unroll
        for (int i = 0; i < 4; i++) {
            int node = nb + tn * 4 + i;
            if (node >= n) break;
            float4 oa, ob;
            oa.x = c2a[i][0] + bav[0]; oa.y = c2a[i][1] + bav[1];
            oa.z = c2a[i][2] + bav[2]; oa.w = c2a[i][3] + bav[3];
            *(float4*)&h[(size_t)node * 124 + tf * 4] = oa;
            if (tf < 15) {
                ob.x = c2b[i][0] + bbv[0]; ob.y = c2b[i][1] + bbv[1];
                ob.z = c2b[i][2] + bbv[2]; ob.w = c2b[i][3] + bbv[3];
                *(float4*)&h[(size_t)node * 124 + 64 + tf * 4] = ob;
            }
        }
    }
}

// ---------------------------------------------------------------------------
// Pooling phase A: G*PARTS blocks; block (g,r) reduces an interleaved slice
// of graph g's contiguous node range into partial[g][r][128] (max/min/sum).
// Graph bounds found by inline binary search on the sorted batch vector.
// ---------------------------------------------------------------------------
__global__ __launch_bounds__(512) void k_pool_a(
    const float* __restrict__ h, const int* __restrict__ batch,
    float* __restrict__ pmax, float* __restrict__ pmin, float* __restrict__ psum,
    int n) {
    int g = blockIdx.x / PARTS, r = blockIdx.x % PARTS;
    __shared__ int sb[2];
    if (threadIdx.x < 2) {
        int target = g + threadIdx.x;
        int lo = 0, hi = n;
        while (lo < hi) {
            int mid = (lo + hi) >> 1;
            if (batch[mid] < target) lo = mid + 1; else hi = mid;
        }
        sb[threadIdx.x] = lo;
    }
    __syncthreads();
    int start = sb[0], end = sb[1];
    int t = threadIdx.x;
    int f = t & 127, r2 = t >> 7;  // r2 in 0..3
    float vmax = -INFINITY, vmin = INFINITY, vsum = 0.f;
    if (f < 124) {
        for (int node = start + r * 4 + r2; node < end; node += PARTS * 4) {
            float v = h[(size_t)node * 124 + f];
            vmax = fmaxf(vmax, v);
            vmin = fminf(vmin, v);
            vsum += v;
        }
    }
    __shared__ float smax[4][128], smin[4][128], ssum[4][128];
    smax[r2][f] = vmax; smin[r2][f] = vmin; ssum[r2][f] = vsum;
    __syncthreads();
    if (r2 == 0) {
        #pragma unroll
        for (int k = 1; k < 4; k++) {
            vmax = fmaxf(vmax, smax[k][f]);
            vmin = fminf(vmin, smin[k][f]);
            vsum += ssum[k][f];
        }
        int idx = (g * PARTS + r) * 128 + f;
        pmax[idx] = vmax; pmin[idx] = vmin; psum[idx] = vsum;
    }
}

// ---------------------------------------------------------------------------
// Fused pooling-fold + head, one block per graph:
//  grelu row (496) built in LDS from the PARTS partials + epilogue, then
//  g1 = grelu@nn2_W + nn2_b (NO relu);  conv4 == plain linear;
//  g2 = relu(g1@W4+b4); g3 = relu(g2@nn3_W+nn3_b); out = g3@nn4_W + nn4_b
// ---------------------------------------------------------------------------
__global__ __launch_bounds__(256) void k_head(
    const float* __restrict__ pmax, const float* __restrict__ pmin,
    const float* __restrict__ psum, const int* __restrict__ batch,
    const float* __restrict__ nn2W, const float* __restrict__ nn2b,
    const float* __restrict__ W4,   const float* __restrict__ b4,
    const float* __restrict__ nn3W, const float* __restrict__ nn3b,
    const float* __restrict__ nn4W, const float* __restrict__ nn4b,
    float* __restrict__ out, int n) {
    int g = blockIdx.x, tid = threadIdx.x;
    int lane = tid & 63, w = tid >> 6;
    __shared__ float lg[496];
    __shared__ float part[4][64];
    __shared__ int sb[2];
    if (tid < 2) {
        int target = g + tid;
        int lo = 0, hi = n;
        while (lo < hi) {
            int mid = (lo + hi) >> 1;
            if (batch[mid] < target) lo = mid + 1; else hi = mid;
        }
        sb[tid] = lo;
    }
    __syncthreads();
    if (tid < 124) {
        float vmax = -INFINITY, vmin = INFINITY, vsum = 0.f;
        #pragma unroll 4
        for (int r = 0; r < PARTS; r++) {
            int idx = (g * PARTS + r) * 128 + tid;
            vmax = fmaxf(vmax, pmax[idx]);
            vmin = fminf(vmin, pmin[idx]);
            vsum += psum[idx];
        }
        int cnt = sb[1] - sb[0];
        float a = (cnt > 0) ? vmax : 0.f;
        float b = (cnt > 0) ? vmin : 0.f;
        lg[tid]       = fmaxf(a, 0.f);
        lg[124 + tid] = fmaxf(b, 0.f);
        lg[248 + tid] = fmaxf(vsum, 0.f);
        lg[372 + tid] = fmaxf(vsum / fmaxf((float)cnt, 1.f), 0.f);
    }
    __syncthreads();
    float acc = 0.f;
    int k0 = w * 124;
    #pragma unroll 4
    for (int k = k0; k < k0 + 124; k++)
        acc += lg[k] * nn2W[k * 64 + lane];
    part[w][lane] = acc;
    __syncthreads();
    if (w == 0) {
        float g1 = part[0][lane] + part[1][lane] + part[2][lane] + part[3][lane]
                 + nn2b[lane];
        float acc2 = (lane < 32) ? b4[lane] : 0.f;
        #pragma unroll 8
        for (int k = 0; k < 64; k++) {
            float v = __shfl(g1, k);
            if (lane < 32) acc2 += v * W4[k * 32 + lane];
        }
        float g2 = fmaxf(acc2, 0.f);
        float acc3 = (lane < 16) ? nn3b[lane] : 0.f;
        #pragma unroll 8
        for (int k = 0; k < 32; k++) {
            float v = __shfl(g2, k);
            if (lane < 16) acc3 += v * nn3W[k * 16 + lane];
        }
        float g3 = fmaxf(acc3, 0.f);
        float p = (lane < 16) ? g3 * nn4W[lane] : 0.f;
        p += __shfl_xor(p, 8);
        p += __shfl_xor(p, 4);
        p += __shfl_xor(p, 2);
        p += __shfl_xor(p, 1);
        if (lane == 0) out[g] = p + nn4b[0];
    }
}

// ---------------------------------------------------------------------------
extern "C" void kernel_launch(void* const* d_in, const int* in_sizes, int n_in,
                              void* d_out, int out_size, void* d_ws, size_t ws_size,
                              hipStream_t stream) {
    const int N = N_NODES, E = N_EDGES, G = N_GRAPHS;

    const float* x     = (const float*)d_in[0];
    const int*   ei    = (const int*)d_in[1];
    const int*   batch = (const int*)d_in[2];
    const float* W1    = (const float*)d_in[3];
    const float* b1    = (const float*)d_in[4];
    const float* W2    = (const float*)d_in[5];
    const float* b2    = (const float*)d_in[6];
    const float* nn1W  = (const float*)d_in[7];
    const float* nn1b  = (const float*)d_in[8];
    const float* nn2W  = (const float*)d_in[9];
    const float* nn2b  = (const float*)d_in[10];
    const float* W4    = (const float*)d_in[11];
    const float* b4    = (const float*)d_in[12];
    const float* nn3W  = (const float*)d_in[13];
    const float* nn3b  = (const float*)d_in[14];
    const float* nn4W  = (const float*)d_in[15];
    const float* nn4b  = (const float*)d_in[16];

    const int* src = ei;       // edge_index[0]
    const int* dst = ei + E;   // edge_index[1]

    char* ws = (char*)d_ws;
    size_t off = 0;
    auto alloc = [&](size_t bytes) -> char* {
        char* p = ws + off;
        off += (bytes + 255) & ~(size_t)255;
        return p;
    };
    int*   deg     = (int*)  alloc((size_t)N * 4);
    float* dinv    = (float*)alloc((size_t)N * 4);
    int*   row_ptr = (int*)  alloc((size_t)(N + 1) * 4);
    int*   slotpos = (int*)  alloc((size_t)E * 4);
    int*   bsum    = (int*)  alloc(1024 * 4);
    int*   csr_src = (int*)  alloc((size_t)E * 4);
    float* y0      = (float*)alloc((size_t)N * 8 * 4);
    float* y1      = (float*)alloc((size_t)N * 32 * 4);
    float* sv      = (float*)alloc((size_t)N * 32 * 4);
    float* h       = (float*)alloc((size_t)N * 124 * 4);
    float* pmax    = (float*)alloc((size_t)G * PARTS * 128 * 4);
    float* pmin    = (float*)alloc((size_t)G * PARTS * 128 * 4);
    float* psum    = (float*)alloc((size_t)G * PARTS * 128 * 4);
    (void)ws_size;

    float* out = (float*)d_out;

    const int NB = (N + SCAN_B - 1) / SCAN_B;  // 98
    const int NCHUNK = 256;                    // edge-list chunks per XCD slice

    hipMemsetAsync(deg, 0, (size_t)N * 4, stream);
    k_degslot<<<(E + 255) / 256, 256, 0, stream>>>(dst, deg, slotpos, E);
    k_block_sums<<<NB, SCAN_B, 0, stream>>>(deg, bsum, N);
    k_scan_bsums<<<1, 256, 0, stream>>>(bsum, NB);
    k_scan_final<<<NB, SCAN_B, 0, stream>>>(deg, bsum, x, row_ptr, dinv, y0, N, E);
    k_fill_x<<<NCHUNK * 8, 256, 0, stream>>>(src, dst, slotpos, row_ptr, csr_src, E, NCHUNK);
    k_agg1<<<(N + 3) / 4, 256, 0, stream>>>(row_ptr, csr_src, y0, dinv, W1, b1, y1, N);
    k_agg2g<<<(N + 3) / 4, 256, 0, stream>>>(row_ptr, csr_src, y1, dinv, sv, N);
    k_l2mm<<<(N + 63) / 64, 256, 0, stream>>>(sv, W2, b2, nn1W, nn1b, h, N);
    k_pool_a<<<G * PARTS, 512, 0, stream>>>(h, batch, pmax, pmin, psum, N);
    k_head<<<G, 256, 0, stream>>>(pmax, pmin, psum, batch, nn2W, nn2b, W4, b4,
                                  nn3W, nn3b, nn4W, nn4b, out, N);
}

// Round 10
// 301.523 us; speedup vs baseline: 1.4110x; 1.1487x over previous
//
#include <hip/hip_runtime.h>
#include <hip/hip_bf16.h>
#include <math.h>

// Problem constants (from reference)
#define N_NODES  100000
#define N_EDGES  1200000
#define N_GRAPHS 100
#define NPB      512                    // nodes per bucket (node >> 9)
#define NBK      196                    // ceil(100000/512)
#define BA       256                    // blocks for hist/scatter passes
#define PARTS    16                     // pooling partials per graph

// ---------------------------------------------------------------------------
// CSR build as a 2-level counting sort — ZERO global atomics.
//  k_hist:    per-block LDS hist over 196 buckets -> hcnt[blk][bkt] coalesced
//  k_bstart:  bucket totals + exclusive scan -> bstart[0..196]; row_ptr[N]=E
//  k_bdist:   per-bucket scan across the 256 blocks -> absolute bases in hcnt
//  k_scatter: LDS-rank scatter of (dst,src) int2 into bucket-sorted pairs[]
//  k_bucket:  per-bucket: LDS hist(512)+scan -> row_ptr/dinv/y0 coalesced,
//             then LDS-rank scatter csr_src into the bucket's L2-local region
// ---------------------------------------------------------------------------
__global__ __launch_bounds__(1024) void k_hist(
    const int* __restrict__ dst, int* __restrict__ hcnt, int e) {
    __shared__ int hist[NBK];
    int blk = blockIdx.x;
    for (int j = threadIdx.x; j < NBK; j += 1024) hist[j] = 0;
    __syncthreads();
    int per = (e + BA - 1) / BA;
    int beg = blk * per;
    int end = beg + per < e ? beg + per : e;
    for (int i = beg + threadIdx.x; i < end; i += 1024)
        atomicAdd(&hist[dst[i] >> 9], 1);
    __syncthreads();
    for (int j = threadIdx.x; j < NBK; j += 1024) hcnt[blk * NBK + j] = hist[j];
}

__global__ __launch_bounds__(256) void k_bstart(
    const int* __restrict__ hcnt, int* __restrict__ bstart,
    int* __restrict__ row_ptr, int e) {
    int b = threadIdx.x;
    int s = 0;
    if (b < NBK) {
        #pragma unroll 8
        for (int blk = 0; blk < BA; blk++) s += hcnt[blk * NBK + b];
    }
    __shared__ int sc[256];
    sc[b] = s;
    __syncthreads();
    for (int d = 1; d < 256; d <<= 1) {
        int u = (b >= d) ? sc[b - d] : 0;
        __syncthreads();
        sc[b] += u;
        __syncthreads();
    }
    if (b < NBK) bstart[b] = sc[b] - s;  // exclusive
    if (b == 0) { bstart[NBK] = e; row_ptr[N_NODES] = e; }
}

__global__ __launch_bounds__(256) void k_bdist(
    int* __restrict__ hcnt, const int* __restrict__ bstart) {
    int b = blockIdx.x, t = threadIdx.x;
    int v = hcnt[t * NBK + b];
    __shared__ int sc[256];
    sc[t] = v;
    __syncthreads();
    for (int d = 1; d < 256; d <<= 1) {
        int u = (t >= d) ? sc[t - d] : 0;
        __syncthreads();
        sc[t] += u;
        __syncthreads();
    }
    hcnt[t * NBK + b] = bstart[b] + (sc[t] - v);
}

__global__ __launch_bounds__(1024) void k_scatter(
    const int* __restrict__ src, const int* __restrict__ dst,
    const int* __restrict__ hcnt, int2* __restrict__ pairs, int e) {
    __shared__ int lbase[NBK];
    __shared__ int cnt[NBK];
    int blk = blockIdx.x;
    for (int j = threadIdx.x; j < NBK; j += 1024) {
        lbase[j] = hcnt[blk * NBK + j];
        cnt[j] = 0;
    }
    __syncthreads();
    int per = (e + BA - 1) / BA;
    int beg = blk * per;
    int end = beg + per < e ? beg + per : e;
    for (int i = beg + threadIdx.x; i < end; i += 1024) {
        int d = dst[i], s = src[i];
        int b = d >> 9;
        int r = atomicAdd(&cnt[b], 1);
        pairs[lbase[b] + r] = make_int2(d, s);
    }
}

__global__ __launch_bounds__(512) void k_bucket(
    const int2* __restrict__ pairs, const int* __restrict__ bstart,
    const float* __restrict__ x,
    int* __restrict__ row_ptr, float* __restrict__ dinv,
    float* __restrict__ y0, int* __restrict__ csr_src, int n) {
    __shared__ int hist[NPB];
    __shared__ int labs[NPB];
    __shared__ int wsum[8], woff[8];
    int b = blockIdx.x, t = threadIdx.x;
    int beg = bstart[b], end = bstart[b + 1];
    hist[t] = 0;
    __syncthreads();
    for (int i = beg + t; i < end; i += 512)
        atomicAdd(&hist[pairs[i].x & (NPB - 1)], 1);
    __syncthreads();
    int v = hist[t];
    int lane = t & 63, w = t >> 6;
    int inc = v;
    #pragma unroll
    for (int d = 1; d < 64; d <<= 1) {
        int u = __shfl_up(inc, d);
        if (lane >= d) inc += u;
    }
    if (lane == 63) wsum[w] = inc;
    __syncthreads();
    if (t == 0) {
        int s = 0;
        #pragma unroll
        for (int k = 0; k < 8; k++) { woff[k] = s; s += wsum[k]; }
    }
    __syncthreads();
    int excl = woff[w] + inc - v;
    labs[t] = beg + excl;
    int node = (b << 9) + t;
    if (node < n) {
        row_ptr[node] = beg + excl;
        float di = rsqrtf((float)(v + 1));   // +1 self loop
        dinv[node] = di;
        float4 q0, q1;
        q0.x = x[(size_t)node * 5 + 0] * di;
        q0.y = x[(size_t)node * 5 + 1] * di;
        q0.z = x[(size_t)node * 5 + 2] * di;
        q0.w = x[(size_t)node * 5 + 3] * di;
        q1.x = x[(size_t)node * 5 + 4] * di;
        q1.y = 0.f; q1.z = 0.f; q1.w = 0.f;
        *(float4*)&y0[(size_t)node * 8]     = q0;
        *(float4*)&y0[(size_t)node * 8 + 4] = q1;
    }
    __syncthreads();
    hist[t] = 0;
    __syncthreads();
    for (int i = beg + t; i < end; i += 512) {
        int2 p = pairs[i];
        int j = p.x & (NPB - 1);
        int r = atomicAdd(&hist[j], 1);
        csr_src[labs[j] + r] = p.y;
    }
}

// ---------------------------------------------------------------------------
// Layer 1: s0 = (A+I) y0;  h1 = relu((dinv*s0)@W1 + b1);  y1 = dinv*h1  [N,32]
// one wave per node; 64 lanes = 8 edges x 8 feats (y0 stride 8, 3.2MB -> L2)
// ---------------------------------------------------------------------------
__global__ __launch_bounds__(256) void k_agg1(
    const int* __restrict__ row_ptr, const int* __restrict__ csr_src,
    const float* __restrict__ y0, const float* __restrict__ dinv,
    const float* __restrict__ W1, const float* __restrict__ b1,
    float* __restrict__ y1, int n) {
    int wave = (blockIdx.x * blockDim.x + threadIdx.x) >> 6;
    if (wave >= n) return;
    int lane = threadIdx.x & 63;
    int f = lane & 7, ec = lane >> 3;
    int start = row_ptr[wave], end = row_ptr[wave + 1];
    float acc = 0.f;
    for (int e = start + ec; e < end; e += 8) {
        int s = csr_src[e];
        acc += y0[(size_t)s * 8 + f];
    }
    if (ec == 0) acc += y0[(size_t)wave * 8 + f];   // self loop
    acc += __shfl_down(acc, 32);
    acc += __shfl_down(acc, 16);
    acc += __shfl_down(acc, 8);
    float di = dinv[wave];
    float s0[5];
    #pragma unroll
    for (int k = 0; k < 5; k++) s0[k] = __shfl(acc, k) * di;
    int fo = lane & 31;
    float hv = b1[fo];
    #pragma unroll
    for (int k = 0; k < 5; k++) hv += s0[k] * W1[k * 32 + fo];
    hv = hv > 0.f ? hv : 0.f;
    if (lane < 32) y1[(size_t)wave * 32 + lane] = hv * di;
}

// ---------------------------------------------------------------------------
// Layer 2 gather only:  sv = dinv * ((A+I) y1)   [N,32]
// one wave per node; 64 lanes = 8 edges (ec) x 8 float4-quads (fq) ->
// 16B/lane gathers; 2-way unroll = 16 edges in flight.
// ---------------------------------------------------------------------------
__global__ __launch_bounds__(256) void k_agg2g(
    const int* __restrict__ row_ptr, const int* __restrict__ csr_src,
    const float* __restrict__ y1, const float* __restrict__ dinv,
    float* __restrict__ sv, int n) {
    int wave = (blockIdx.x * blockDim.x + threadIdx.x) >> 6;
    if (wave >= n) return;
    int lane = threadIdx.x & 63;
    int ec = lane >> 3, fq = lane & 7;
    int start = row_ptr[wave], end = row_ptr[wave + 1];
    float4 a0 = make_float4(0.f, 0.f, 0.f, 0.f);
    float4 a1 = make_float4(0.f, 0.f, 0.f, 0.f);
    int e = start + ec;
    for (; e + 8 < end; e += 16) {
        int s0 = csr_src[e], s1 = csr_src[e + 8];
        float4 v0 = *(const float4*)&y1[(size_t)s0 * 32 + fq * 4];
        float4 v1 = *(const float4*)&y1[(size_t)s1 * 32 + fq * 4];
        a0.x += v0.x; a0.y += v0.y; a0.z += v0.z; a0.w += v0.w;
        a1.x += v1.x; a1.y += v1.y; a1.z += v1.z; a1.w += v1.w;
    }
    for (; e < end; e += 8) {
        int s0 = csr_src[e];
        float4 v0 = *(const float4*)&y1[(size_t)s0 * 32 + fq * 4];
        a0.x += v0.x; a0.y += v0.y; a0.z += v0.z; a0.w += v0.w;
    }
    a0.x += a1.x; a0.y += a1.y; a0.z += a1.z; a0.w += a1.w;
    if (ec == 0) {   // self loop
        float4 sl = *(const float4*)&y1[(size_t)wave * 32 + fq * 4];
        a0.x += sl.x; a0.y += sl.y; a0.z += sl.z; a0.w += sl.w;
    }
    a0.x += __shfl_down(a0.x, 32); a0.y += __shfl_down(a0.y, 32);
    a0.z += __shfl_down(a0.z, 32); a0.w += __shfl_down(a0.w, 32);
    a0.x += __shfl_down(a0.x, 16); a0.y += __shfl_down(a0.y, 16);
    a0.z += __shfl_down(a0.z, 16); a0.w += __shfl_down(a0.w, 16);
    a0.x += __shfl_down(a0.x, 8);  a0.y += __shfl_down(a0.y, 8);
    a0.z += __shfl_down(a0.z, 8);  a0.w += __shfl_down(a0.w, 8);
    if (lane < 8) {
        float di = dinv[wave];
        float4 r;
        r.x = a0.x * di; r.y = a0.y * di; r.z = a0.z * di; r.w = a0.w * di;
        *(float4*)&sv[(size_t)wave * 32 + fq * 4] = r;
    }
}

// ---------------------------------------------------------------------------
// Fused dense part of layer 2 as register-tiled f32 GEMM, 64-node tiles:
//   h2 = relu(sv @ W2 + b2)   [64 x 64]   (kept transposed in LDS)
//   h  = h2 @ nn1W + nn1b     [64 x 124]
// ---------------------------------------------------------------------------
#define LTS 68   // padded row stride for transposed tiles (x4B, 16B-aligned)
__global__ __launch_bounds__(256) void k_l2mm(
    const float* __restrict__ sv, const float* __restrict__ W2,
    const float* __restrict__ b2, const float* __restrict__ nn1W,
    const float* __restrict__ nn1b, float* __restrict__ h, int n) {
    __shared__ float lsW2[32 * 64];      // [k][f] stride 64, 8 KB
    __shared__ float lsN[64 * 128];      // [k][f] stride 128 (124 padded), 32 KB
    __shared__ float lsT[64 * LTS];      // union: svT[32][.] then h2T[64][.], 17.4 KB

    int tid = threadIdx.x;
    int nb = blockIdx.x * 64;

    #pragma unroll
    for (int i = 0; i < 8; i++) lsW2[tid + i * 256] = W2[tid + i * 256];
    for (int idx = tid; idx < 64 * 124; idx += 256)
        lsN[(idx / 124) * 128 + (idx % 124)] = nn1W[idx];
    if (tid < 256) lsN[(tid >> 2) * 128 + 124 + (tid & 3)] = 0.f;
    {
        int node = tid >> 2, kq = (tid & 3) * 8;
        float4 v0, v1;
        if (nb + node < n) {
            v0 = *(const float4*)&sv[(size_t)(nb + node) * 32 + kq];
            v1 = *(const float4*)&sv[(size_t)(nb + node) * 32 + kq + 4];
        } else {
            v0 = make_float4(0.f, 0.f, 0.f, 0.f); v1 = v0;
        }
        lsT[(kq + 0) * LTS + node] = v0.x;
        lsT[(kq + 1) * LTS + node] = v0.y;
        lsT[(kq + 2) * LTS + node] = v0.z;
        lsT[(kq + 3) * LTS + node] = v0.w;
        lsT[(kq + 4) * LTS + node] = v1.x;
        lsT[(kq + 5) * LTS + node] = v1.y;
        lsT[(kq + 6) * LTS + node] = v1.z;
        lsT[(kq + 7) * LTS + node] = v1.w;
    }
    __syncthreads();

    int tf = tid & 15;   // feature quad
    int tn = tid >> 4;   // node quad

    float c1[4][4] = {};
    #pragma unroll 4
    for (int k = 0; k < 32; k++) {
        float4 a = *(const float4*)&lsT[k * LTS + tn * 4];
        float4 w = *(const float4*)&lsW2[k * 64 + tf * 4];
        const float av[4] = {a.x, a.y, a.z, a.w};
        const float wv[4] = {w.x, w.y, w.z, w.w};
        #pragma unroll
        for (int i = 0; i < 4; i++)
            #pragma unroll
            for (int j = 0; j < 4; j++) c1[i][j] += av[i] * wv[j];
    }
    __syncthreads();
    {
        float4 bb = *(const float4*)&b2[tf * 4];
        const float bv[4] = {bb.x, bb.y, bb.z, bb.w};
        #pragma unroll
        for (int j = 0; j < 4; j++) {
            float4 col;
            col.x = fmaxf(c1[0][j] + bv[j], 0.f);
            col.y = fmaxf(c1[1][j] + bv[j], 0.f);
            col.z = fmaxf(c1[2][j] + bv[j], 0.f);
            col.w = fmaxf(c1[3][j] + bv[j], 0.f);
            *(float4*)&lsT[(tf * 4 + j) * LTS + tn * 4] = col;
        }
    }
    __syncthreads();

    float c2a[4][4] = {}, c2b[4][4] = {};
    #pragma unroll 2
    for (int k = 0; k < 64; k++) {
        float4 a  = *(const float4*)&lsT[k * LTS + tn * 4];
        float4 w1 = *(const float4*)&lsN[k * 128 + tf * 4];
        float4 w2 = *(const float4*)&lsN[k * 128 + 64 + tf * 4];
        const float av[4] = {a.x, a.y, a.z, a.w};
        const float w1v[4] = {w1.x, w1.y, w1.z, w1.w};
        const float w2v[4] = {w2.x, w2.y, w2.z, w2.w};
        #pragma unroll
        for (int i = 0; i < 4; i++)
            #pragma unroll
            for (int j = 0; j < 4; j++) {
                c2a[i][j] += av[i] * w1v[j];
                c2b[i][j] += av[i] * w2v[j];
            }
    }
    {
        float4 ba = *(const float4*)&nn1b[tf * 4];
        const float bav[4] = {ba.x, ba.y, ba.z, ba.w};
        float bbv[4] = {0.f, 0.f, 0.f, 0.f};
        if (tf < 15) {
            float4 bb = *(const float4*)&nn1b[64 + tf * 4];
            bbv[0] = bb.x; bbv[1] = bb.y; bbv[2] = bb.z; bbv[3] = bb.w;
        }
        #pragma unroll
        for (int i = 0; i < 4; i++) {
            int node = nb + tn * 4 + i;
            if (node >= n) break;
            float4 oa, ob;
            oa.x = c2a[i][0] + bav[0]; oa.y = c2a[i][1] + bav[1];
            oa.z = c2a[i][2] + bav[2]; oa.w = c2a[i][3] + bav[3];
            *(float4*)&h[(size_t)node * 124 + tf * 4] = oa;
            if (tf < 15) {
                ob.x = c2b[i][0] + bbv[0]; ob.y = c2b[i][1] + bbv[1];
                ob.z = c2b[i][2] + bbv[2]; ob.w = c2b[i][3] + bbv[3];
                *(float4*)&h[(size_t)node * 124 + 64 + tf * 4] = ob;
            }
        }
    }
}

// ---------------------------------------------------------------------------
// Pooling phase A: G*PARTS blocks; block (g,r) reduces an interleaved slice
// of graph g's contiguous node range into partial[g][r][128] (max/min/sum).
// ---------------------------------------------------------------------------
__global__ __launch_bounds__(512) void k_pool_a(
    const float* __restrict__ h, const int* __restrict__ batch,
    float* __restrict__ pmax, float* __restrict__ pmin, float* __restrict__ psum,
    int n) {
    int g = blockIdx.x / PARTS, r = blockIdx.x % PARTS;
    __shared__ int sb[2];
    if (threadIdx.x < 2) {
        int target = g + threadIdx.x;
        int lo = 0, hi = n;
        while (lo < hi) {
            int mid = (lo + hi) >> 1;
            if (batch[mid] < target) lo = mid + 1; else hi = mid;
        }
        sb[threadIdx.x] = lo;
    }
    __syncthreads();
    int start = sb[0], end = sb[1];
    int t = threadIdx.x;
    int f = t & 127, r2 = t >> 7;  // r2 in 0..3
    float vmax = -INFINITY, vmin = INFINITY, vsum = 0.f;
    if (f < 124) {
        for (int node = start + r * 4 + r2; node < end; node += PARTS * 4) {
            float v = h[(size_t)node * 124 + f];
            vmax = fmaxf(vmax, v);
            vmin = fminf(vmin, v);
            vsum += v;
        }
    }
    __shared__ float smax[4][128], smin[4][128], ssum[4][128];
    smax[r2][f] = vmax; smin[r2][f] = vmin; ssum[r2][f] = vsum;
    __syncthreads();
    if (r2 == 0) {
        #pragma unroll
        for (int k = 1; k < 4; k++) {
            vmax = fmaxf(vmax, smax[k][f]);
            vmin = fminf(vmin, smin[k][f]);
            vsum += ssum[k][f];
        }
        int idx = (g * PARTS + r) * 128 + f;
        pmax[idx] = vmax; pmin[idx] = vmin; psum[idx] = vsum;
    }
}

// ---------------------------------------------------------------------------
// Fused pooling-fold + head, one block per graph.
// ---------------------------------------------------------------------------
__global__ __launch_bounds__(256) void k_head(
    const float* __restrict__ pmax, const float* __restrict__ pmin,
    const float* __restrict__ psum, const int* __restrict__ batch,
    const float* __restrict__ nn2W, const float* __restrict__ nn2b,
    const float* __restrict__ W4,   const float* __restrict__ b4,
    const float* __restrict__ nn3W, const float* __restrict__ nn3b,
    const float* __restrict__ nn4W, const float* __restrict__ nn4b,
    float* __restrict__ out, int n) {
    int g = blockIdx.x, tid = threadIdx.x;
    int lane = tid & 63, w = tid >> 6;
    __shared__ float lg[496];
    __shared__ float part[4][64];
    __shared__ int sb[2];
    if (tid < 2) {
        int target = g + tid;
        int lo = 0, hi = n;
        while (lo < hi) {
            int mid = (lo + hi) >> 1;
            if (batch[mid] < target) lo = mid + 1; else hi = mid;
        }
        sb[tid] = lo;
    }
    __syncthreads();
    if (tid < 124) {
        float vmax = -INFINITY, vmin = INFINITY, vsum = 0.f;
        #pragma unroll 4
        for (int r = 0; r < PARTS; r++) {
            int idx = (g * PARTS + r) * 128 + tid;
            vmax = fmaxf(vmax, pmax[idx]);
            vmin = fminf(vmin, pmin[idx]);
            vsum += psum[idx];
        }
        int cnt = sb[1] - sb[0];
        float a = (cnt > 0) ? vmax : 0.f;
        float b = (cnt > 0) ? vmin : 0.f;
        lg[tid]       = fmaxf(a, 0.f);
        lg[124 + tid] = fmaxf(b, 0.f);
        lg[248 + tid] = fmaxf(vsum, 0.f);
        lg[372 + tid] = fmaxf(vsum / fmaxf((float)cnt, 1.f), 0.f);
    }
    __syncthreads();
    float acc = 0.f;
    int k0 = w * 124;
    #pragma unroll 4
    for (int k = k0; k < k0 + 124; k++)
        acc += lg[k] * nn2W[k * 64 + lane];
    part[w][lane] = acc;
    __syncthreads();
    if (w == 0) {
        float g1 = part[0][lane] + part[1][lane] + part[2][lane] + part[3][lane]
                 + nn2b[lane];
        float acc2 = (lane < 32) ? b4[lane] : 0.f;
        #pragma unroll 8
        for (int k = 0; k < 64; k++) {
            float v = __shfl(g1, k);
            if (lane < 32) acc2 += v * W4[k * 32 + lane];
        }
        float g2 = fmaxf(acc2, 0.f);
        float acc3 = (lane < 16) ? nn3b[lane] : 0.f;
        #pragma unroll 8
        for (int k = 0; k < 32; k++) {
            float v = __shfl(g2, k);
            if (lane < 16) acc3 += v * nn3W[k * 16 + lane];
        }
        float g3 = fmaxf(acc3, 0.f);
        float p = (lane < 16) ? g3 * nn4W[lane] : 0.f;
        p += __shfl_xor(p, 8);
        p += __shfl_xor(p, 4);
        p += __shfl_xor(p, 2);
        p += __shfl_xor(p, 1);
        if (lane == 0) out[g] = p + nn4b[0];
    }
}

// ---------------------------------------------------------------------------
extern "C" void kernel_launch(void* const* d_in, const int* in_sizes, int n_in,
                              void* d_out, int out_size, void* d_ws, size_t ws_size,
                              hipStream_t stream) {
    const int N = N_NODES, E = N_EDGES, G = N_GRAPHS;

    const float* x     = (const float*)d_in[0];
    const int*   ei    = (const int*)d_in[1];
    const int*   batch = (const int*)d_in[2];
    const float* W1    = (const float*)d_in[3];
    const float* b1    = (const float*)d_in[4];
    const float* W2    = (const float*)d_in[5];
    const float* b2    = (const float*)d_in[6];
    const float* nn1W  = (const float*)d_in[7];
    const float* nn1b  = (const float*)d_in[8];
    const float* nn2W  = (const float*)d_in[9];
    const float* nn2b  = (const float*)d_in[10];
    const float* W4    = (const float*)d_in[11];
    const float* b4    = (const float*)d_in[12];
    const float* nn3W  = (const float*)d_in[13];
    const float* nn3b  = (const float*)d_in[14];
    const float* nn4W  = (const float*)d_in[15];
    const float* nn4b  = (const float*)d_in[16];

    const int* src = ei;       // edge_index[0]
    const int* dst = ei + E;   // edge_index[1]

    char* ws = (char*)d_ws;
    size_t off = 0;
    auto alloc = [&](size_t bytes) -> char* {
        char* p = ws + off;
        off += (bytes + 255) & ~(size_t)255;
        return p;
    };
    int*   hcnt    = (int*)  alloc((size_t)BA * NBK * 4);
    int*   bstart  = (int*)  alloc((NBK + 1) * 4);
    int2*  pairs   = (int2*) alloc((size_t)E * 8);
    int*   row_ptr = (int*)  alloc((size_t)(N + 1) * 4);
    float* dinv    = (float*)alloc((size_t)N * 4);
    int*   csr_src = (int*)  alloc((size_t)E * 4);
    float* y0      = (float*)alloc((size_t)N * 8 * 4);
    float* y1      = (float*)alloc((size_t)N * 32 * 4);
    float* sv      = (float*)alloc((size_t)N * 32 * 4);
    float* h       = (float*)alloc((size_t)N * 124 * 4);
    float* pmax    = (float*)alloc((size_t)G * PARTS * 128 * 4);
    float* pmin    = (float*)alloc((size_t)G * PARTS * 128 * 4);
    float* psum    = (float*)alloc((size_t)G * PARTS * 128 * 4);
    (void)ws_size;

    float* out = (float*)d_out;

    k_hist<<<BA, 1024, 0, stream>>>(dst, hcnt, E);
    k_bstart<<<1, 256, 0, stream>>>(hcnt, bstart, row_ptr, E);
    k_bdist<<<NBK, 256, 0, stream>>>(hcnt, bstart);
    k_scatter<<<BA, 1024, 0, stream>>>(src, dst, hcnt, pairs, E);
    k_bucket<<<NBK, 512, 0, stream>>>(pairs, bstart, x, row_ptr, dinv, y0, csr_src, N);
    k_agg1<<<(N + 3) / 4, 256, 0, stream>>>(row_ptr, csr_src, y0, dinv, W1, b1, y1, N);
    k_agg2g<<<(N + 3) / 4, 256, 0, stream>>>(row_ptr, csr_src, y1, dinv, sv, N);
    k_l2mm<<<(N + 63) / 64, 256, 0, stream>>>(sv, W2, b2, nn1W, nn1b, h, N);
    k_pool_a<<<G * PARTS, 512, 0, stream>>>(h, batch, pmax, pmin, psum, N);
    k_head<<<G, 256, 0, stream>>>(pmax, pmin, psum, batch, nn2W, nn2b, W4, b4,
                                  nn3W, nn3b, nn4W, nn4b, out, N);
}

// Round 13
// 295.005 us; speedup vs baseline: 1.4422x; 1.0221x over previous
//
#include <hip/hip_runtime.h>
#include <hip/hip_bf16.h>
#include <math.h>

// Problem constants (from reference)
#define N_NODES  100000
#define N_EDGES  1200000
#define N_GRAPHS 100
#define NPB      512                    // nodes per bucket (node >> 9)
#define NBK      196                    // ceil(100000/512)
#define BA       256                    // blocks for hist/scatter passes
#define PARTS    16                     // pooling partials per graph

// ---------------------------------------------------------------------------
// CSR build as a 2-level counting sort — ZERO global atomics.
//  k_hist:    per-block LDS hist over 196 buckets -> hcnt[blk][bkt] coalesced
//  k_bstart:  bucket totals + exclusive scan -> bstart[0..196]; row_ptr[N]=E
//  k_bdist:   per-bucket scan across the 256 blocks -> absolute bases in hcnt
//  k_scatter: LDS-rank scatter of (dst,src) int2 into bucket-sorted pairs[]
//  k_bucket:  per-bucket: LDS hist(512)+scan -> row_ptr/dinv/y0 coalesced,
//             then LDS-rank scatter csr_src into the bucket's L2-local region
// ---------------------------------------------------------------------------
__global__ __launch_bounds__(1024) void k_hist(
    const int* __restrict__ dst, int* __restrict__ hcnt, int e) {
    __shared__ int hist[NBK];
    int blk = blockIdx.x;
    for (int j = threadIdx.x; j < NBK; j += 1024) hist[j] = 0;
    __syncthreads();
    int per = (e + BA - 1) / BA;
    int beg = blk * per;
    int end = beg + per < e ? beg + per : e;
    for (int i = beg + threadIdx.x; i < end; i += 1024)
        atomicAdd(&hist[dst[i] >> 9], 1);
    __syncthreads();
    for (int j = threadIdx.x; j < NBK; j += 1024) hcnt[blk * NBK + j] = hist[j];
}

__global__ __launch_bounds__(256) void k_bstart(
    const int* __restrict__ hcnt, int* __restrict__ bstart,
    int* __restrict__ row_ptr, int e) {
    int b = threadIdx.x;
    int s = 0;
    if (b < NBK) {
        #pragma unroll 8
        for (int blk = 0; blk < BA; blk++) s += hcnt[blk * NBK + b];
    }
    __shared__ int sc[256];
    sc[b] = s;
    __syncthreads();
    for (int d = 1; d < 256; d <<= 1) {
        int u = (b >= d) ? sc[b - d] : 0;
        __syncthreads();
        sc[b] += u;
        __syncthreads();
    }
    if (b < NBK) bstart[b] = sc[b] - s;  // exclusive
    if (b == 0) { bstart[NBK] = e; row_ptr[N_NODES] = e; }
}

__global__ __launch_bounds__(256) void k_bdist(
    int* __restrict__ hcnt, const int* __restrict__ bstart) {
    int b = blockIdx.x, t = threadIdx.x;
    int v = hcnt[t * NBK + b];
    __shared__ int sc[256];
    sc[t] = v;
    __syncthreads();
    for (int d = 1; d < 256; d <<= 1) {
        int u = (t >= d) ? sc[t - d] : 0;
        __syncthreads();
        sc[t] += u;
        __syncthreads();
    }
    hcnt[t * NBK + b] = bstart[b] + (sc[t] - v);
}

__global__ __launch_bounds__(1024) void k_scatter(
    const int* __restrict__ src, const int* __restrict__ dst,
    const int* __restrict__ hcnt, int2* __restrict__ pairs, int e) {
    __shared__ int lbase[NBK];
    __shared__ int cnt[NBK];
    int blk = blockIdx.x;
    for (int j = threadIdx.x; j < NBK; j += 1024) {
        lbase[j] = hcnt[blk * NBK + j];
        cnt[j] = 0;
    }
    __syncthreads();
    int per = (e + BA - 1) / BA;
    int beg = blk * per;
    int end = beg + per < e ? beg + per : e;
    for (int i = beg + threadIdx.x; i < end; i += 1024) {
        int d = dst[i], s = src[i];
        int b = d >> 9;
        int r = atomicAdd(&cnt[b], 1);
        pairs[lbase[b] + r] = make_int2(d, s);
    }
}

__global__ __launch_bounds__(512) void k_bucket(
    const int2* __restrict__ pairs, const int* __restrict__ bstart,
    const float* __restrict__ x,
    int* __restrict__ row_ptr, float* __restrict__ dinv,
    float* __restrict__ y0, int* __restrict__ csr_src, int n) {
    __shared__ int hist[NPB];
    __shared__ int labs[NPB];
    __shared__ int wsum[8], woff[8];
    int b = blockIdx.x, t = threadIdx.x;
    int beg = bstart[b], end = bstart[b + 1];
    hist[t] = 0;
    __syncthreads();
    for (int i = beg + t; i < end; i += 512)
        atomicAdd(&hist[pairs[i].x & (NPB - 1)], 1);
    __syncthreads();
    int v = hist[t];
    int lane = t & 63, w = t >> 6;
    int inc = v;
    #pragma unroll
    for (int d = 1; d < 64; d <<= 1) {
        int u = __shfl_up(inc, d);
        if (lane >= d) inc += u;
    }
    if (lane == 63) wsum[w] = inc;
    __syncthreads();
    if (t == 0) {
        int s = 0;
        #pragma unroll
        for (int k = 0; k < 8; k++) { woff[k] = s; s += wsum[k]; }
    }
    __syncthreads();
    int excl = woff[w] + inc - v;
    labs[t] = beg + excl;
    int node = (b << 9) + t;
    if (node < n) {
        row_ptr[node] = beg + excl;
        float di = rsqrtf((float)(v + 1));   // +1 self loop
        dinv[node] = di;
        float4 q0, q1;
        q0.x = x[(size_t)node * 5 + 0] * di;
        q0.y = x[(size_t)node * 5 + 1] * di;
        q0.z = x[(size_t)node * 5 + 2] * di;
        q0.w = x[(size_t)node * 5 + 3] * di;
        q1.x = x[(size_t)node * 5 + 4] * di;
        q1.y = 0.f; q1.z = 0.f; q1.w = 0.f;
        *(float4*)&y0[(size_t)node * 8]     = q0;
        *(float4*)&y0[(size_t)node * 8 + 4] = q1;
    }
    __syncthreads();
    hist[t] = 0;
    __syncthreads();
    for (int i = beg + t; i < end; i += 512) {
        int2 p = pairs[i];
        int j = p.x & (NPB - 1);
        int r = atomicAdd(&hist[j], 1);
        csr_src[labs[j] + r] = p.y;
    }
}

// ---------------------------------------------------------------------------
// Layer 1: s0 = (A+I) y0;  h1 = relu((dinv*s0)@W1 + b1);  y1 = dinv*h1  [N,32]
// one wave per node; 64 lanes = 8 edges x 8 feats (y0 stride 8, 3.2MB -> L2)
// ---------------------------------------------------------------------------
__global__ __launch_bounds__(256) void k_agg1(
    const int* __restrict__ row_ptr, const int* __restrict__ csr_src,
    const float* __restrict__ y0, const float* __restrict__ dinv,
    const float* __restrict__ W1, const float* __restrict__ b1,
    float* __restrict__ y1, int n) {
    int wave = (blockIdx.x * blockDim.x + threadIdx.x) >> 6;
    if (wave >= n) return;
    int lane = threadIdx.x & 63;
    int f = lane & 7, ec = lane >> 3;
    int start = row_ptr[wave], end = row_ptr[wave + 1];
    float acc = 0.f;
    for (int e = start + ec; e < end; e += 8) {
        int s = csr_src[e];
        acc += y0[(size_t)s * 8 + f];
    }
    if (ec == 0) acc += y0[(size_t)wave * 8 + f];   // self loop
    acc += __shfl_down(acc, 32);
    acc += __shfl_down(acc, 16);
    acc += __shfl_down(acc, 8);
    float di = dinv[wave];
    float s0[5];
    #pragma unroll
    for (int k = 0; k < 5; k++) s0[k] = __shfl(acc, k) * di;
    int fo = lane & 31;
    float hv = b1[fo];
    #pragma unroll
    for (int k = 0; k < 5; k++) hv += s0[k] * W1[k * 32 + fo];
    hv = hv > 0.f ? hv : 0.f;
    if (lane < 32) y1[(size_t)wave * 32 + lane] = hv * di;
}

// ---------------------------------------------------------------------------
// Layer 2 gather only:  sv = dinv * ((A+I) y1)   [N,32]
// one wave per node; 64 lanes = 8 edges (ec) x 8 float4-quads (fq) ->
// 16B/lane gathers; 2-way unroll = 16 edges in flight.
// ---------------------------------------------------------------------------
__global__ __launch_bounds__(256) void k_agg2g(
    const int* __restrict__ row_ptr, const int* __restrict__ csr_src,
    const float* __restrict__ y1, const float* __restrict__ dinv,
    float* __restrict__ sv, int n) {
    int wave = (blockIdx.x * blockDim.x + threadIdx.x) >> 6;
    if (wave >= n) return;
    int lane = threadIdx.x & 63;
    int ec = lane >> 3, fq = lane & 7;
    int start = row_ptr[wave], end = row_ptr[wave + 1];
    float4 a0 = make_float4(0.f, 0.f, 0.f, 0.f);
    float4 a1 = make_float4(0.f, 0.f, 0.f, 0.f);
    int e = start + ec;
    for (; e + 8 < end; e += 16) {
        int s0 = csr_src[e], s1 = csr_src[e + 8];
        float4 v0 = *(const float4*)&y1[(size_t)s0 * 32 + fq * 4];
        float4 v1 = *(const float4*)&y1[(size_t)s1 * 32 + fq * 4];
        a0.x += v0.x; a0.y += v0.y; a0.z += v0.z; a0.w += v0.w;
        a1.x += v1.x; a1.y += v1.y; a1.z += v1.z; a1.w += v1.w;
    }
    for (; e < end; e += 8) {
        int s0 = csr_src[e];
        float4 v0 = *(const float4*)&y1[(size_t)s0 * 32 + fq * 4];
        a0.x += v0.x; a0.y += v0.y; a0.z += v0.z; a0.w += v0.w;
    }
    a0.x += a1.x; a0.y += a1.y; a0.z += a1.z; a0.w += a1.w;
    if (ec == 0) {   // self loop
        float4 sl = *(const float4*)&y1[(size_t)wave * 32 + fq * 4];
        a0.x += sl.x; a0.y += sl.y; a0.z += sl.z; a0.w += sl.w;
    }
    a0.x += __shfl_down(a0.x, 32); a0.y += __shfl_down(a0.y, 32);
    a0.z += __shfl_down(a0.z, 32); a0.w += __shfl_down(a0.w, 32);
    a0.x += __shfl_down(a0.x, 16); a0.y += __shfl_down(a0.y, 16);
    a0.z += __shfl_down(a0.z, 16); a0.w += __shfl_down(a0.w, 16);
    a0.x += __shfl_down(a0.x, 8);  a0.y += __shfl_down(a0.y, 8);
    a0.z += __shfl_down(a0.z, 8);  a0.w += __shfl_down(a0.w, 8);
    if (lane < 8) {
        float di = dinv[wave];
        float4 r;
        r.x = a0.x * di; r.y = a0.y * di; r.z = a0.z * di; r.w = a0.w * di;
        *(float4*)&sv[(size_t)wave * 32 + fq * 4] = r;
    }
}

// ---------------------------------------------------------------------------
// Fused dense part of layer 2 as register-tiled f32 GEMM, 64-node tiles:
//   h2 = relu(sv @ W2 + b2)   [64 x 64]   (kept transposed in LDS)
//   h  = h2 @ nn1W + nn1b     [64 x 124]
// nn1W is NOT staged in LDS: it is identical across all 1563 blocks -> L2-hot;
// reading it from global in the k-loop cuts LDS 58->26KB, lifting occupancy
// from 2 to 4 blocks/CU (the R10 profile showed 15% occupancy as the limit,
// bank conflicts were only ~4% of cycles).
// ---------------------------------------------------------------------------
#define LTS 68   // padded row stride for transposed tiles (x4B, 16B-aligned)
__global__ __launch_bounds__(256, 4) void k_l2mm(
    const float* __restrict__ sv, const float* __restrict__ W2,
    const float* __restrict__ b2, const float* __restrict__ nn1W,
    const float* __restrict__ nn1b, float* __restrict__ h, int n) {
    __shared__ float lsW2[32 * 64];      // [k][f] stride 64, 8 KB
    __shared__ float lsT[64 * LTS];      // union: svT[32][.] then h2T[64][.], 17.4 KB

    int tid = threadIdx.x;
    int nb = blockIdx.x * 64;

    #pragma unroll
    for (int i = 0; i < 8; i++) lsW2[tid + i * 256] = W2[tid + i * 256];
    {
        int node = tid >> 2, kq = (tid & 3) * 8;
        float4 v0, v1;
        if (nb + node < n) {
            v0 = *(const float4*)&sv[(size_t)(nb + node) * 32 + kq];
            v1 = *(const float4*)&sv[(size_t)(nb + node) * 32 + kq + 4];
        } else {
            v0 = make_float4(0.f, 0.f, 0.f, 0.f); v1 = v0;
        }
        lsT[(kq + 0) * LTS + node] = v0.x;
        lsT[(kq + 1) * LTS + node] = v0.y;
        lsT[(kq + 2) * LTS + node] = v0.z;
        lsT[(kq + 3) * LTS + node] = v0.w;
        lsT[(kq + 4) * LTS + node] = v1.x;
        lsT[(kq + 5) * LTS + node] = v1.y;
        lsT[(kq + 6) * LTS + node] = v1.z;
        lsT[(kq + 7) * LTS + node] = v1.w;
    }
    __syncthreads();

    int tf = tid & 15;   // feature quad
    int tn = tid >> 4;   // node quad

    float c1[4][4] = {};
    #pragma unroll 4
    for (int k = 0; k < 32; k++) {
        float4 a = *(const float4*)&lsT[k * LTS + tn * 4];
        float4 w = *(const float4*)&lsW2[k * 64 + tf * 4];
        const float av[4] = {a.x, a.y, a.z, a.w};
        const float wv[4] = {w.x, w.y, w.z, w.w};
        #pragma unroll
        for (int i = 0; i < 4; i++)
            #pragma unroll
            for (int j = 0; j < 4; j++) c1[i][j] += av[i] * wv[j];
    }
    __syncthreads();
    {
        float4 bb = *(const float4*)&b2[tf * 4];
        const float bv[4] = {bb.x, bb.y, bb.z, bb.w};
        #pragma unroll
        for (int j = 0; j < 4; j++) {
            float4 col;
            col.x = fmaxf(c1[0][j] + bv[j], 0.f);
            col.y = fmaxf(c1[1][j] + bv[j], 0.f);
            col.z = fmaxf(c1[2][j] + bv[j], 0.f);
            col.w = fmaxf(c1[3][j] + bv[j], 0.f);
            *(float4*)&lsT[(tf * 4 + j) * LTS + tn * 4] = col;
        }
    }
    __syncthreads();

    // GEMM2: weights straight from global (L2-broadcast, same addrs each block)
    float c2a[4][4] = {}, c2b[4][4] = {};
    #pragma unroll 2
    for (int k = 0; k < 64; k++) {
        float4 a = *(const float4*)&lsT[k * LTS + tn * 4];
        float4 w1 = *(const float4*)&nn1W[k * 124 + tf * 4];
        float4 w2 = make_float4(0.f, 0.f, 0.f, 0.f);
        if (tf < 15) w2 = *(const float4*)&nn1W[k * 124 + 64 + tf * 4];
        const float av[4] = {a.x, a.y, a.z, a.w};
        const float w1v[4] = {w1.x, w1.y, w1.z, w1.w};
        const float w2v[4] = {w2.x, w2.y, w2.z, w2.w};
        #pragma unroll
        for (int i = 0; i < 4; i++)
            #pragma unroll
            for (int j = 0; j < 4; j++) {
                c2a[i][j] += av[i] * w1v[j];
                c2b[i][j] += av[i] * w2v[j];
            }
    }
    {
        float4 ba = *(const float4*)&nn1b[tf * 4];
        const float bav[4] = {ba.x, ba.y, ba.z, ba.w};
        float bbv[4] = {0.f, 0.f, 0.f, 0.f};
        if (tf < 15) {
            float4 bb = *(const float4*)&nn1b[64 + tf * 4];
            bbv[0] = bb.x; bbv[1] = bb.y; bbv[2] = bb.z; bbv[3] = bb.w;
        }
        #pragma unroll
        for (int i = 0; i < 4; i++) {
            int node = nb + tn * 4 + i;
            if (node >= n) break;
            float4 oa, ob;
            oa.x = c2a[i][0] + bav[0]; oa.y = c2a[i][1] + bav[1];
            oa.z = c2a[i][2] + bav[2]; oa.w = c2a[i][3] + bav[3];
            *(float4*)&h[(size_t)node * 124 + tf * 4] = oa;
            if (tf < 15) {
                ob.x = c2b[i][0] + bbv[0]; ob.y = c2b[i][1] + bbv[1];
                ob.z = c2b[i][2] + bbv[2]; ob.w = c2b[i][3] + bbv[3];
                *(float4*)&h[(size_t)node * 124 + 64 + tf * 4] = ob;
            }
        }
    }
}

// ---------------------------------------------------------------------------
// Pooling phase A: G*PARTS blocks; block (g,r) reduces an interleaved slice
// of graph g's contiguous node range into partial[g][r][128] (max/min/sum).
// ---------------------------------------------------------------------------
__global__ __launch_bounds__(512) void k_pool_a(
    const float* __restrict__ h, const int* __restrict__ batch,
    float* __restrict__ pmax, float* __restrict__ pmin, float* __restrict__ psum,
    int n) {
    int g = blockIdx.x / PARTS, r = blockIdx.x % PARTS;
    __shared__ int sb[2];
    if (threadIdx.x < 2) {
        int target = g + threadIdx.x;
        int lo = 0, hi = n;
        while (lo < hi) {
            int mid = (lo + hi) >> 1;
            if (batch[mid] < target) lo = mid + 1; else hi = mid;
        }
        sb[threadIdx.x] = lo;
    }
    __syncthreads();
    int start = sb[0], end = sb[1];
    int t = threadIdx.x;
    int f = t & 127, r2 = t >> 7;  // r2 in 0..3
    float vmax = -INFINITY, vmin = INFINITY, vsum = 0.f;
    if (f < 124) {
        for (int node = start + r * 4 + r2; node < end; node += PARTS * 4) {
            float v = h[(size_t)node * 124 + f];
            vmax = fmaxf(vmax, v);
            vmin = fminf(vmin, v);
            vsum += v;
        }
    }
    __shared__ float smax[4][128], smin[4][128], ssum[4][128];
    smax[r2][f] = vmax; smin[r2][f] = vmin; ssum[r2][f] = vsum;
    __syncthreads();
    if (r2 == 0) {
        #pragma unroll
        for (int k = 1; k < 4; k++) {
            vmax = fmaxf(vmax, smax[k][f]);
            vmin = fminf(vmin, smin[k][f]);
            vsum += ssum[k][f];
        }
        int idx = (g * PARTS + r) * 128 + f;
        pmax[idx] = vmax; pmin[idx] = vmin; psum[idx] = vsum;
    }
}

// ---------------------------------------------------------------------------
// Fused pooling-fold + head, one block per graph.
// ---------------------------------------------------------------------------
__global__ __launch_bounds__(256) void k_head(
    const float* __restrict__ pmax, const float* __restrict__ pmin,
    const float* __restrict__ psum, const int* __restrict__ batch,
    const float* __restrict__ nn2W, const float* __restrict__ nn2b,
    const float* __restrict__ W4,   const float* __restrict__ b4,
    const float* __restrict__ nn3W, const float* __restrict__ nn3b,
    const float* __restrict__ nn4W, const float* __restrict__ nn4b,
    float* __restrict__ out, int n) {
    int g = blockIdx.x, tid = threadIdx.x;
    int lane = tid & 63, w = tid >> 6;
    __shared__ float lg[496];
    __shared__ float part[4][64];
    __shared__ int sb[2];
    if (tid < 2) {
        int target = g + tid;
        int lo = 0, hi = n;
        while (lo < hi) {
            int mid = (lo + hi) >> 1;
            if (batch[mid] < target) lo = mid + 1; else hi = mid;
        }
        sb[tid] = lo;
    }
    __syncthreads();
    if (tid < 124) {
        float vmax = -INFINITY, vmin = INFINITY, vsum = 0.f;
        #pragma unroll 4
        for (int r = 0; r < PARTS; r++) {
            int idx = (g * PARTS + r) * 128 + tid;
            vmax = fmaxf(vmax, pmax[idx]);
            vmin = fminf(vmin, pmin[idx]);
            vsum += psum[idx];
        }
        int cnt = sb[1] - sb[0];
        float a = (cnt > 0) ? vmax : 0.f;
        float b = (cnt > 0) ? vmin : 0.f;
        lg[tid]       = fmaxf(a, 0.f);
        lg[124 + tid] = fmaxf(b, 0.f);
        lg[248 + tid] = fmaxf(vsum, 0.f);
        lg[372 + tid] = fmaxf(vsum / fmaxf((float)cnt, 1.f), 0.f);
    }
    __syncthreads();
    float acc = 0.f;
    int k0 = w * 124;
    #pragma unroll 4
    for (int k = k0; k < k0 + 124; k++)
        acc += lg[k] * nn2W[k * 64 + lane];
    part[w][lane] = acc;
    __syncthreads();
    if (w == 0) {
        float g1 = part[0][lane] + part[1][lane] + part[2][lane] + part[3][lane]
                 + nn2b[lane];
        float acc2 = (lane < 32) ? b4[lane] : 0.f;
        #pragma unroll 8
        for (int k = 0; k < 64; k++) {
            float v = __shfl(g1, k);
            if (lane < 32) acc2 += v * W4[k * 32 + lane];
        }
        float g2 = fmaxf(acc2, 0.f);
        float acc3 = (lane < 16) ? nn3b[lane] : 0.f;
        #pragma unroll 8
        for (int k = 0; k < 32; k++) {
            float v = __shfl(g2, k);
            if (lane < 16) acc3 += v * nn3W[k * 16 + lane];
        }
        float g3 = fmaxf(acc3, 0.f);
        float p = (lane < 16) ? g3 * nn4W[lane] : 0.f;
        p += __shfl_xor(p, 8);
        p += __shfl_xor(p, 4);
        p += __shfl_xor(p, 2);
        p += __shfl_xor(p, 1);
        if (lane == 0) out[g] = p + nn4b[0];
    }
}

// ---------------------------------------------------------------------------
extern "C" void kernel_launch(void* const* d_in, const int* in_sizes, int n_in,
                              void* d_out, int out_size, void* d_ws, size_t ws_size,
                              hipStream_t stream) {
    const int N = N_NODES, E = N_EDGES, G = N_GRAPHS;

    const float* x     = (const float*)d_in[0];
    const int*   ei    = (const int*)d_in[1];
    const int*   batch = (const int*)d_in[2];
    const float* W1    = (const float*)d_in[3];
    const float* b1    = (const float*)d_in[4];
    const float* W2    = (const float*)d_in[5];
    const float* b2    = (const float*)d_in[6];
    const float* nn1W  = (const float*)d_in[7];
    const float* nn1b  = (const float*)d_in[8];
    const float* nn2W  = (const float*)d_in[9];
    const float* nn2b  = (const float*)d_in[10];
    const float* W4    = (const float*)d_in[11];
    const float* b4    = (const float*)d_in[12];
    const float* nn3W  = (const float*)d_in[13];
    const float* nn3b  = (const float*)d_in[14];
    const float* nn4W  = (const float*)d_in[15];
    const float* nn4b  = (const float*)d_in[16];

    const int* src = ei;       // edge_index[0]
    const int* dst = ei + E;   // edge_index[1]

    char* ws = (char*)d_ws;
    size_t off = 0;
    auto alloc = [&](size_t bytes) -> char* {
        char* p = ws + off;
        off += (bytes + 255) & ~(size_t)255;
        return p;
    };
    int*   hcnt    = (int*)  alloc((size_t)BA * NBK * 4);
    int*   bstart  = (int*)  alloc((NBK + 1) * 4);
    int2*  pairs   = (int2*) alloc((size_t)E * 8);
    int*   row_ptr = (int*)  alloc((size_t)(N + 1) * 4);
    float* dinv    = (float*)alloc((size_t)N * 4);
    int*   csr_src = (int*)  alloc((size_t)E * 4);
    float* y0      = (float*)alloc((size_t)N * 8 * 4);
    float* y1      = (float*)alloc((size_t)N * 32 * 4);
    float* sv      = (float*)alloc((size_t)N * 32 * 4);
    float* h       = (float*)alloc((size_t)N * 124 * 4);
    float* pmax    = (float*)alloc((size_t)G * PARTS * 128 * 4);
    float* pmin    = (float*)alloc((size_t)G * PARTS * 128 * 4);
    float* psum    = (float*)alloc((size_t)G * PARTS * 128 * 4);
    (void)ws_size;

    float* out = (float*)d_out;

    k_hist<<<BA, 1024, 0, stream>>>(dst, hcnt, E);
    k_bstart<<<1, 256, 0, stream>>>(hcnt, bstart, row_ptr, E);
    k_bdist<<<NBK, 256, 0, stream>>>(hcnt, bstart);
    k_scatter<<<BA, 1024, 0, stream>>>(src, dst, hcnt, pairs, E);
    k_bucket<<<NBK, 512, 0, stream>>>(pairs, bstart, x, row_ptr, dinv, y0, csr_src, N);
    k_agg1<<<(N + 3) / 4, 256, 0, stream>>>(row_ptr, csr_src, y0, dinv, W1, b1, y1, N);
    k_agg2g<<<(N + 3) / 4, 256, 0, stream>>>(row_ptr, csr_src, y1, dinv, sv, N);
    k_l2mm<<<(N + 63) / 64, 256, 0, stream>>>(sv, W2, b2, nn1W, nn1b, h, N);
    k_pool_a<<<G * PARTS, 512, 0, stream>>>(h, batch, pmax, pmin, psum, N);
    k_head<<<G, 256, 0, stream>>>(pmax, pmin, psum, batch, nn2W, nn2b, W4, b4,
                                  nn3W, nn3b, nn4W, nn4b, out, N);
}